// Round 1
// baseline (236.715 us; speedup 1.0000x reference)
//
#include <hip/hip_runtime.h>
#include <hip/hip_bf16.h>

// Problem constants (fixed by the reference's setup_inputs)
#define BATCH   2
#define NPTS    16384   // N
#define NQ      4096    // P
#define CFEAT   64
#define NS      32      // nsample
#define R2      0.01f   // radius^2
#define COUT    (3 + CFEAT)   // 67

// One wave (64 threads) per query point.
// Phase 1: ballot-scan first NS in-ball indices in index order (early exit).
// Phase 2: write 67 channels x 32 samples; lane = (half, s), 2 channels/iter.
__global__ __launch_bounds__(64) void qg_kernel(
    const float* __restrict__ xyz,      // (B, N, 3)
    const float* __restrict__ new_xyz,  // (B, P, 3)
    const float* __restrict__ feat,     // (B, C, N)
    float* __restrict__ out)            // (B, 67, P, S)
{
    const int bp   = blockIdx.x;        // 0 .. B*P-1
    const int b    = bp >> 12;          // / NQ
    const int p    = bp & (NQ - 1);
    const int lane = threadIdx.x;       // 0..63

    __shared__ int idx_s[NS];

    // Query point (same for all lanes; scalar-cached loads)
    const float qx = new_xyz[bp * 3 + 0];
    const float qy = new_xyz[bp * 3 + 1];
    const float qz = new_xyz[bp * 3 + 2];

    const float* xb = xyz + (size_t)b * NPTS * 3;

    // ---- Phase 1: ordered ball-query scan ----
    int cnt = 0;
    for (int base = 0; base < NPTS; base += 64) {
        const int j = base + lane;
        const float dx = xb[j * 3 + 0] - qx;
        const float dy = xb[j * 3 + 1] - qy;
        const float dz = xb[j * 3 + 2] - qz;
        const float d2 = dx * dx + dy * dy + dz * dz;
        const bool hit = d2 < R2;
        const unsigned long long m = __ballot(hit);
        if (hit) {
            const int slot = cnt + __popcll(m & ((1ull << lane) - 1ull));
            if (slot < NS) idx_s[slot] = j;
        }
        cnt += __popcll(m);
        if (cnt >= NS) break;   // wave-uniform (cnt from ballot)
    }
    __syncthreads();

    // Padding: slots [cnt, NS) get first-found index (0 if none found)
    if (cnt < NS) {
        const int first = (cnt > 0) ? idx_s[0] : 0;
        if (lane >= cnt && lane < NS) idx_s[lane] = first;
    }
    __syncthreads();

    // ---- Phase 2: grouping ----
    const int s    = lane & 31;
    const int half = lane >> 5;         // 0 or 1
    const int j    = idx_s[s];

    const float* fb = feat + (size_t)b * CFEAT * NPTS;
    // out[((b*COUT + c)*NQ + p)*NS + s]
    const size_t out_bp = ((size_t)b * COUT * NQ + (size_t)p) * NS + s;

    #pragma unroll 4
    for (int c = half; c < COUT; c += 2) {
        float v;
        if (c < 3) {
            const float qc = (c == 0) ? qx : ((c == 1) ? qy : qz);
            v = xb[j * 3 + c] - qc;
        } else {
            v = fb[(c - 3) * NPTS + j];
        }
        out[out_bp + (size_t)c * (NQ * NS)] = v;
    }
}

extern "C" void kernel_launch(void* const* d_in, const int* in_sizes, int n_in,
                              void* d_out, int out_size, void* d_ws, size_t ws_size,
                              hipStream_t stream) {
    const float* xyz     = (const float*)d_in[0];  // (2,16384,3)
    const float* new_xyz = (const float*)d_in[1];  // (2,4096,3)
    const float* feat    = (const float*)d_in[2];  // (2,64,16384)
    float* out = (float*)d_out;                    // (2,67,4096,32)

    const int nblocks = BATCH * NQ;                // 8192
    qg_kernel<<<nblocks, 64, 0, stream>>>(xyz, new_xyz, feat, out);
}

// Round 2
// 171.571 us; speedup vs baseline: 1.3797x; 1.3797x over previous
//
#include <hip/hip_runtime.h>
#include <hip/hip_bf16.h>

#define BATCH   2
#define NPTS    16384   // N
#define NQ      4096    // P
#define CFEAT   64
#define NS      32      // nsample
#define R2      0.01f   // radius^2
#define COUT    (3 + CFEAT)   // 67

// ---------------- feature transpose: (B,C,N) -> (B,N,C) ----------------
// Reads coalesced along N (256B/inst); writes 16-B segments (all useful bytes).
__global__ __launch_bounds__(256) void transpose_kernel(
    const float* __restrict__ feat, float4* __restrict__ featT4)
{
    const int g = blockIdx.x * 256 + threadIdx.x;   // 0 .. B*N-1
    const int b = g >> 14;                          // / NPTS
    const float* fb = feat + (size_t)b * CFEAT * NPTS + (g & (NPTS - 1));
    float4* dst = featT4 + (size_t)g * 16;          // 64 floats = 16 float4
    #pragma unroll
    for (int pass = 0; pass < 4; ++pass) {
        float v[16];
        #pragma unroll
        for (int k = 0; k < 16; ++k)
            v[k] = fb[(size_t)(pass * 16 + k) * NPTS];
        #pragma unroll
        for (int q = 0; q < 4; ++q)
            dst[pass * 4 + q] = make_float4(v[4*q], v[4*q+1], v[4*q+2], v[4*q+3]);
    }
}

// ---------------- main kernel: 4 queries per 256-thread block ----------------
__global__ __launch_bounds__(256) void qg_main(
    const float* __restrict__ xyz,      // (B, N, 3)
    const float* __restrict__ new_xyz,  // (B, P, 3)
    const float* __restrict__ feat,     // (B, C, N)   (fallback path)
    const float4* __restrict__ featT4,  // (B, N, C)   (transposed path)
    float* __restrict__ out,            // (B, 67, P, S)
    int use_t)
{
    const int wave = threadIdx.x >> 6;
    const int lane = threadIdx.x & 63;
    const int bp   = blockIdx.x * 4 + wave;
    const int b    = bp >> 12;
    const int p    = bp & (NQ - 1);

    __shared__ int idx_s[4][NS];

    const float qx = new_xyz[bp * 3 + 0];
    const float qy = new_xyz[bp * 3 + 1];
    const float qz = new_xyz[bp * 3 + 2];
    const float* xb = xyz + (size_t)b * NPTS * 3;

    // ---- Phase 1: ordered ball-query scan, 128 pts/iter ----
    int cnt = 0;
    const unsigned long long below = (1ull << lane) - 1ull;
    for (int base = 0; base < NPTS; base += 128) {
        const int j0 = base + lane;
        const int j1 = j0 + 64;
        const float x0 = xb[j0*3+0], y0 = xb[j0*3+1], z0 = xb[j0*3+2];
        const float x1 = xb[j1*3+0], y1 = xb[j1*3+1], z1 = xb[j1*3+2];
        const float dx0 = x0-qx, dy0 = y0-qy, dz0 = z0-qz;
        const float dx1 = x1-qx, dy1 = y1-qy, dz1 = z1-qz;
        const bool h0 = dx0*dx0 + dy0*dy0 + dz0*dz0 < R2;
        const bool h1 = dx1*dx1 + dy1*dy1 + dz1*dz1 < R2;
        const unsigned long long m0 = __ballot(h0);
        const unsigned long long m1 = __ballot(h1);
        if (h0) {
            const int slot = cnt + __popcll(m0 & below);
            if (slot < NS) idx_s[wave][slot] = j0;
        }
        const int c0 = __popcll(m0);
        if (h1) {
            const int slot = cnt + c0 + __popcll(m1 & below);
            if (slot < NS) idx_s[wave][slot] = j1;
        }
        cnt += c0 + __popcll(m1);
        if (cnt >= NS) break;       // wave-uniform
    }
    __builtin_amdgcn_wave_barrier();

    if (cnt < NS) {
        const int first = (cnt > 0) ? idx_s[wave][0] : 0;
        if (lane >= cnt && lane < NS) idx_s[wave][lane] = first;
    }
    __builtin_amdgcn_wave_barrier();

    const size_t cstride = (size_t)NQ * NS;
    const size_t out_q   = ((size_t)b * COUT * NQ + (size_t)p) * NS;

    // ---- xyz channels (0..2): lanes 0..31, contiguous 128-B stores ----
    if (lane < NS) {
        const int j = idx_s[wave][lane];
        out[out_q + 0*cstride + lane] = xb[j*3+0] - qx;
        out[out_q + 1*cstride + lane] = xb[j*3+1] - qy;
        out[out_q + 2*cstride + lane] = xb[j*3+2] - qz;
    }

    // ---- feature channels ----
    if (use_t) {
        // lane = (soff 0..3, cg 0..15): float4 gather of 4 consecutive channels
        const int cg   = lane & 15;
        const int soff = lane >> 4;
        #pragma unroll
        for (int it = 0; it < 8; ++it) {
            const int s = it * 4 + soff;
            const int j = idx_s[wave][s];
            const float4 v = featT4[((size_t)b * NPTS + j) * 16 + cg];
            const size_t o = out_q + (size_t)(3 + cg * 4) * cstride + s;
            out[o              ] = v.x;
            out[o +     cstride] = v.y;
            out[o + 2 * cstride] = v.z;
            out[o + 3 * cstride] = v.w;
        }
    } else {
        // fallback: direct (C,N) gather
        const float* fb = feat + (size_t)b * CFEAT * NPTS;
        const int s    = lane & 31;
        const int half = lane >> 5;
        const int j    = idx_s[wave][s];
        #pragma unroll 8
        for (int c = half; c < CFEAT; c += 2) {
            out[out_q + (size_t)(3 + c) * cstride + s] = fb[(size_t)c * NPTS + j];
        }
    }
}

extern "C" void kernel_launch(void* const* d_in, const int* in_sizes, int n_in,
                              void* d_out, int out_size, void* d_ws, size_t ws_size,
                              hipStream_t stream) {
    const float* xyz     = (const float*)d_in[0];  // (2,16384,3)
    const float* new_xyz = (const float*)d_in[1];  // (2,4096,3)
    const float* feat    = (const float*)d_in[2];  // (2,64,16384)
    float* out = (float*)d_out;                    // (2,67,4096,32)

    const size_t need = (size_t)BATCH * NPTS * CFEAT * sizeof(float);  // 8 MB
    const int use_t = (ws_size >= need) ? 1 : 0;

    if (use_t) {
        transpose_kernel<<<(BATCH * NPTS) / 256, 256, 0, stream>>>(feat, (float4*)d_ws);
    }
    qg_main<<<(BATCH * NQ) / 4, 256, 0, stream>>>(
        xyz, new_xyz, feat, (const float4*)d_ws, out, use_t);
}

// Round 3
// 153.577 us; speedup vs baseline: 1.5413x; 1.1172x over previous
//
#include <hip/hip_runtime.h>
#include <hip/hip_bf16.h>
#include <climits>

#define BATCH   2
#define NPTS    16384   // N
#define NQ      4096    // P
#define CFEAT   64
#define NS      32      // nsample
#define R2      0.01f   // radius^2
#define COUT    (3 + CFEAT)   // 67
#define GDIM    10      // grid cells per axis (cell size = radius)
#define NCELL   (GDIM * GDIM * GDIM)
#define MAXHITS 256     // per-query hit buffer (ball holds ~68 pts avg)

// ---- ws layout ----
// [0, 8MB)          : featT (B,N,C) float
// ints after 8MB    : cnt[2*1000] | fill[2*1000] | cstart[2*1001] | plist[2*16384]
#define FEATT_BYTES ((size_t)BATCH * NPTS * CFEAT * sizeof(float))
#define OFF_CNT    0
#define OFF_FILL   (2 * NCELL)
#define OFF_CSTART (4 * NCELL)
#define OFF_PLIST  (4 * NCELL + 2 * (NCELL + 1))
#define GRID_INTS  (OFF_PLIST + BATCH * NPTS)

__device__ __forceinline__ int cell_of(float x, float y, float z) {
    int cx = (int)(x * GDIM); cx = cx < 0 ? 0 : (cx > GDIM - 1 ? GDIM - 1 : cx);
    int cy = (int)(y * GDIM); cy = cy < 0 ? 0 : (cy > GDIM - 1 ? GDIM - 1 : cy);
    int cz = (int)(z * GDIM); cz = cz < 0 ? 0 : (cz > GDIM - 1 ? GDIM - 1 : cz);
    return (cz * GDIM + cy) * GDIM + cx;   // x fastest -> contiguous x-runs
}

// ---------------- zero counters ----------------
__global__ __launch_bounds__(256) void zero_kernel(int* p, int n) {
    const int g = blockIdx.x * 256 + threadIdx.x;
    if (g < n) p[g] = 0;
}

// ---------------- count points per cell ----------------
__global__ __launch_bounds__(256) void count_kernel(
    const float* __restrict__ xyz, int* __restrict__ cnt)
{
    const int g = blockIdx.x * 256 + threadIdx.x;   // 0..B*N-1
    const int b = g >> 14;
    const int c = cell_of(xyz[g*3], xyz[g*3+1], xyz[g*3+2]);
    atomicAdd(&cnt[b * NCELL + c], 1);
}

// ---------------- exclusive scan per batch (1000 cells) ----------------
__global__ __launch_bounds__(1024) void scan_kernel(
    const int* __restrict__ cnt, int* __restrict__ cstart)
{
    const int b = blockIdx.x;
    const int t = threadIdx.x;
    __shared__ int s[1024];
    const int v = (t < NCELL) ? cnt[b * NCELL + t] : 0;
    s[t] = v;
    __syncthreads();
    for (int off = 1; off < 1024; off <<= 1) {
        const int u = (t >= off) ? s[t - off] : 0;
        __syncthreads();
        s[t] += u;
        __syncthreads();
    }
    if (t < NCELL) cstart[b * (NCELL + 1) + t] = s[t] - v;
    if (t == NCELL - 1) cstart[b * (NCELL + 1) + NCELL] = s[t];
}

// ---------------- scatter point indices into cell lists ----------------
__global__ __launch_bounds__(256) void scatter_kernel(
    const float* __restrict__ xyz, const int* __restrict__ cstart,
    int* __restrict__ fill, int* __restrict__ plist)
{
    const int g = blockIdx.x * 256 + threadIdx.x;
    const int b = g >> 14;
    const int j = g & (NPTS - 1);
    const int c = cell_of(xyz[g*3], xyz[g*3+1], xyz[g*3+2]);
    const int pos = atomicAdd(&fill[b * NCELL + c], 1);
    plist[b * NPTS + cstart[b * (NCELL + 1) + c] + pos] = j;
}

// ---------------- feature transpose (B,C,N) -> (B,N,C), LDS-tiled ----------------
__global__ __launch_bounds__(256) void transpose_kernel(
    const float* __restrict__ feat, float* __restrict__ featT)
{
    __shared__ float tile[64][65];
    const int n0   = blockIdx.x * 64;
    const int b    = blockIdx.y;
    const int lane = threadIdx.x & 63;
    const int grp  = threadIdx.x >> 6;           // 0..3
    const float* fb = feat + (size_t)b * CFEAT * NPTS;
    #pragma unroll
    for (int k = 0; k < 16; ++k) {
        const int c = grp * 16 + k;
        tile[c][lane] = fb[(size_t)c * NPTS + n0 + lane];
    }
    __syncthreads();
    float* db = featT + ((size_t)b * NPTS + n0) * CFEAT;
    #pragma unroll
    for (int k = 0; k < 16; ++k) {
        const int n = grp * 16 + k;
        db[(size_t)n * CFEAT + lane] = tile[lane][n];
    }
}

// ---------------- main: grid-accelerated ball query + group ----------------
__global__ __launch_bounds__(256) void qg_grid(
    const float* __restrict__ xyz,      // (B, N, 3)
    const float* __restrict__ new_xyz,  // (B, P, 3)
    const float4* __restrict__ featT4,  // (B, N, C)
    const int* __restrict__ cstart,     // (B, NCELL+1)
    const int* __restrict__ plist,      // (B, N)
    float* __restrict__ out)            // (B, 67, P, S)
{
    const int wave = threadIdx.x >> 6;
    const int lane = threadIdx.x & 63;
    const int bp   = blockIdx.x * 4 + wave;
    const int b    = bp >> 12;
    const int p    = bp & (NQ - 1);

    __shared__ int hbuf[4][MAXHITS];
    __shared__ int idx_s[4][NS];

    const float qx = new_xyz[bp * 3 + 0];
    const float qy = new_xyz[bp * 3 + 1];
    const float qz = new_xyz[bp * 3 + 2];
    const float* xb = xyz + (size_t)b * NPTS * 3;
    const int* cs = cstart + b * (NCELL + 1);
    const int* pl = plist + b * NPTS;

    int qcx = (int)(qx * GDIM); qcx = qcx < 0 ? 0 : (qcx > GDIM-1 ? GDIM-1 : qcx);
    int qcy = (int)(qy * GDIM); qcy = qcy < 0 ? 0 : (qcy > GDIM-1 ? GDIM-1 : qcy);
    int qcz = (int)(qz * GDIM); qcz = qcz < 0 ? 0 : (qcz > GDIM-1 ? GDIM-1 : qcz);
    const int x0 = qcx > 0 ? qcx - 1 : 0;
    const int x1 = qcx < GDIM-1 ? qcx + 1 : GDIM-1;
    const int y0 = qcy > 0 ? qcy - 1 : 0;
    const int y1 = qcy < GDIM-1 ? qcy + 1 : GDIM-1;
    const int z0 = qcz > 0 ? qcz - 1 : 0;
    const int z1 = qcz < GDIM-1 ? qcz + 1 : GDIM-1;

    const unsigned long long below = (1ull << lane) - 1ull;
    int hitcnt = 0;

    for (int gz = z0; gz <= z1; ++gz) {
        for (int gy = y0; gy <= y1; ++gy) {
            const int crow = (gz * GDIM + gy) * GDIM;
            const int s = cs[crow + x0];
            const int e = cs[crow + x1 + 1];
            for (int pos = s; pos < e; pos += 64) {
                const int i = pos + lane;
                const bool inr = i < e;
                const int jj = inr ? pl[i] : 0;
                const float dx = xb[jj*3+0] - qx;
                const float dy = xb[jj*3+1] - qy;
                const float dz = xb[jj*3+2] - qz;
                const bool hit = inr && (dx*dx + dy*dy + dz*dz < R2);
                const unsigned long long m = __ballot(hit);
                if (hit) {
                    const int slot = hitcnt + __popcll(m & below);
                    if (slot < MAXHITS) hbuf[wave][slot] = jj;
                }
                hitcnt += __popcll(m);
            }
        }
    }
    __builtin_amdgcn_wave_barrier();

    // ---- select 32 smallest hit indices (== first 32 in index order) ----
    const int nh = hitcnt < MAXHITS ? hitcnt : MAXHITS;
    int v0 = (lane       < nh) ? hbuf[wave][lane      ] : INT_MAX;
    int v1 = (lane +  64 < nh) ? hbuf[wave][lane +  64] : INT_MAX;
    int v2 = (lane + 128 < nh) ? hbuf[wave][lane + 128] : INT_MAX;
    int v3 = (lane + 192 < nh) ? hbuf[wave][lane + 192] : INT_MAX;

    int sel = INT_MAX;
    #pragma unroll
    for (int k = 0; k < NS; ++k) {
        int m4 = min(min(v0, v1), min(v2, v3));
        #pragma unroll
        for (int off = 32; off > 0; off >>= 1)
            m4 = min(m4, __shfl_xor(m4, off));
        if (lane == k) sel = m4;
        v0 = (v0 == m4) ? INT_MAX : v0;
        v1 = (v1 == m4) ? INT_MAX : v1;
        v2 = (v2 == m4) ? INT_MAX : v2;
        v3 = (v3 == m4) ? INT_MAX : v3;
    }
    const int first = __shfl(sel, 0);
    if (lane < NS) {
        int v = sel;
        if (v == INT_MAX) v = (first == INT_MAX) ? 0 : first;
        idx_s[wave][lane] = v;
    }
    __builtin_amdgcn_wave_barrier();

    const size_t cstride = (size_t)NQ * NS;
    const size_t out_q   = ((size_t)b * COUT * NQ + (size_t)p) * NS;

    // xyz channels: lanes 0..31, contiguous 128-B stores
    if (lane < NS) {
        const int j = idx_s[wave][lane];
        out[out_q + 0*cstride + lane] = xb[j*3+0] - qx;
        out[out_q + 1*cstride + lane] = xb[j*3+1] - qy;
        out[out_q + 2*cstride + lane] = xb[j*3+2] - qz;
    }

    // feature channels: lane = (soff 0..3, cg 0..15), float4 gathers
    const int cg   = lane & 15;
    const int soff = lane >> 4;
    #pragma unroll
    for (int it = 0; it < 8; ++it) {
        const int s = it * 4 + soff;
        const int j = idx_s[wave][s];
        const float4 v = featT4[((size_t)b * NPTS + j) * 16 + cg];
        const size_t o = out_q + (size_t)(3 + cg * 4) * cstride + s;
        out[o              ] = v.x;
        out[o +     cstride] = v.y;
        out[o + 2 * cstride] = v.z;
        out[o + 3 * cstride] = v.w;
    }
}

// ---------------- fallback: linear-scan kernel (round-2 version) ----------------
__global__ __launch_bounds__(256) void qg_linear(
    const float* __restrict__ xyz, const float* __restrict__ new_xyz,
    const float* __restrict__ feat, float* __restrict__ out)
{
    const int wave = threadIdx.x >> 6;
    const int lane = threadIdx.x & 63;
    const int bp   = blockIdx.x * 4 + wave;
    const int b    = bp >> 12;
    const int p    = bp & (NQ - 1);
    __shared__ int idx_s[4][NS];
    const float qx = new_xyz[bp*3+0], qy = new_xyz[bp*3+1], qz = new_xyz[bp*3+2];
    const float* xb = xyz + (size_t)b * NPTS * 3;
    int cnt = 0;
    const unsigned long long below = (1ull << lane) - 1ull;
    for (int base = 0; base < NPTS; base += 64) {
        const int j = base + lane;
        const float dx = xb[j*3+0]-qx, dy = xb[j*3+1]-qy, dz = xb[j*3+2]-qz;
        const bool hit = dx*dx+dy*dy+dz*dz < R2;
        const unsigned long long m = __ballot(hit);
        if (hit) {
            const int slot = cnt + __popcll(m & below);
            if (slot < NS) idx_s[wave][slot] = j;
        }
        cnt += __popcll(m);
        if (cnt >= NS) break;
    }
    __builtin_amdgcn_wave_barrier();
    if (cnt < NS) {
        const int first = (cnt > 0) ? idx_s[wave][0] : 0;
        if (lane >= cnt && lane < NS) idx_s[wave][lane] = first;
    }
    __builtin_amdgcn_wave_barrier();
    const size_t cstride = (size_t)NQ * NS;
    const size_t out_q = ((size_t)b * COUT * NQ + (size_t)p) * NS;
    if (lane < NS) {
        const int j = idx_s[wave][lane];
        out[out_q + 0*cstride + lane] = xb[j*3+0] - qx;
        out[out_q + 1*cstride + lane] = xb[j*3+1] - qy;
        out[out_q + 2*cstride + lane] = xb[j*3+2] - qz;
    }
    const float* fb = feat + (size_t)b * CFEAT * NPTS;
    const int s = lane & 31, half = lane >> 5;
    const int j = idx_s[wave][s];
    #pragma unroll 8
    for (int c = half; c < CFEAT; c += 2)
        out[out_q + (size_t)(3 + c) * cstride + s] = fb[(size_t)c * NPTS + j];
}

extern "C" void kernel_launch(void* const* d_in, const int* in_sizes, int n_in,
                              void* d_out, int out_size, void* d_ws, size_t ws_size,
                              hipStream_t stream) {
    const float* xyz     = (const float*)d_in[0];  // (2,16384,3)
    const float* new_xyz = (const float*)d_in[1];  // (2,4096,3)
    const float* feat    = (const float*)d_in[2];  // (2,64,16384)
    float* out = (float*)d_out;                    // (2,67,4096,32)

    const size_t need_full = FEATT_BYTES + (size_t)GRID_INTS * sizeof(int);

    if (ws_size >= need_full) {
        float* featT = (float*)d_ws;
        int* gi = (int*)((char*)d_ws + FEATT_BYTES);
        int* cnt    = gi + OFF_CNT;
        int* fill   = gi + OFF_FILL;
        int* cstart = gi + OFF_CSTART;
        int* plist  = gi + OFF_PLIST;

        zero_kernel<<<(4 * NCELL + 255) / 256, 256, 0, stream>>>(cnt, 4 * NCELL);
        count_kernel<<<(BATCH * NPTS) / 256, 256, 0, stream>>>(xyz, cnt);
        scan_kernel<<<BATCH, 1024, 0, stream>>>(cnt, cstart);
        scatter_kernel<<<(BATCH * NPTS) / 256, 256, 0, stream>>>(xyz, cstart, fill, plist);
        transpose_kernel<<<dim3(NPTS / 64, BATCH), 256, 0, stream>>>(feat, featT);
        qg_grid<<<(BATCH * NQ) / 4, 256, 0, stream>>>(
            xyz, new_xyz, (const float4*)featT, cstart, plist, out);
    } else {
        qg_linear<<<(BATCH * NQ) / 4, 256, 0, stream>>>(xyz, new_xyz, feat, out);
    }
}

// Round 4
// 147.683 us; speedup vs baseline: 1.6029x; 1.0399x over previous
//
#include <hip/hip_runtime.h>
#include <hip/hip_bf16.h>
#include <climits>

#define BATCH   2
#define NPTS    16384   // N
#define NQ      4096    // P
#define CFEAT   64
#define NS      32      // nsample
#define R2      0.01f   // radius^2
#define COUT    (3 + CFEAT)   // 67
#define GDIM    10      // grid cells per axis (cell size = radius)
#define NCELL   (GDIM * GDIM * GDIM)
#define MAXHITS 256     // per-query hit cap (ball holds ~68 pts avg)

// ---- ws layout (bytes) ----
// [0, 8MB)        : featT  (B,N,C) float
// [8MB, +512KB)   : pxyzj  (B,N) float4 {x,y,z,bitcast(j)}  cell-sorted
// then ints       : cnt[2*NCELL] | fill[2*NCELL] | cstart[2*(NCELL+1)]
#define FEATT_BYTES ((size_t)BATCH * NPTS * CFEAT * sizeof(float))
#define PXYZJ_BYTES ((size_t)BATCH * NPTS * sizeof(float4))
#define OFF_CNT    0
#define OFF_FILL   (2 * NCELL)
#define OFF_CSTART (4 * NCELL)
#define GRID_INTS  (4 * NCELL + 2 * (NCELL + 1))

__device__ __forceinline__ int cell_of(float x, float y, float z) {
    int cx = (int)(x * GDIM); cx = cx < 0 ? 0 : (cx > GDIM - 1 ? GDIM - 1 : cx);
    int cy = (int)(y * GDIM); cy = cy < 0 ? 0 : (cy > GDIM - 1 ? GDIM - 1 : cy);
    int cz = (int)(z * GDIM); cz = cz < 0 ? 0 : (cz > GDIM - 1 ? GDIM - 1 : cz);
    return (cz * GDIM + cy) * GDIM + cx;   // x fastest -> contiguous x-runs
}

// ---------------- fused: transpose (blocks 0..511) + count (blocks 512..639) ----
__global__ __launch_bounds__(256) void prep1_kernel(
    const float* __restrict__ feat, float* __restrict__ featT,
    const float* __restrict__ xyz, int* __restrict__ cnt)
{
    __shared__ float tile[64][65];
    if (blockIdx.x < 512) {
        const int b    = blockIdx.x >> 8;
        const int n0   = (blockIdx.x & 255) * 64;
        const int lane = threadIdx.x & 63;
        const int grp  = threadIdx.x >> 6;           // 0..3
        const float* fb = feat + (size_t)b * CFEAT * NPTS;
        #pragma unroll
        for (int k = 0; k < 16; ++k) {
            const int c = grp * 16 + k;
            tile[c][lane] = fb[(size_t)c * NPTS + n0 + lane];
        }
        __syncthreads();
        float* db = featT + ((size_t)b * NPTS + n0) * CFEAT;
        #pragma unroll
        for (int k = 0; k < 16; ++k) {
            const int n = grp * 16 + k;
            db[(size_t)n * CFEAT + lane] = tile[lane][n];
        }
    } else {
        const int g = (blockIdx.x - 512) * 256 + threadIdx.x;   // 0..B*N-1
        const int b = g >> 14;
        const int c = cell_of(xyz[g*3], xyz[g*3+1], xyz[g*3+2]);
        atomicAdd(&cnt[b * NCELL + c], 1);
    }
}

// ---------------- scan (redundant per block, in LDS) + scatter ----------------
__global__ __launch_bounds__(256) void prep2_kernel(
    const float* __restrict__ xyz, const int* __restrict__ cnt,
    int* __restrict__ fill, int* __restrict__ cstart,
    float4* __restrict__ pxyzj)
{
    __shared__ int scs[2 * NCELL];       // exclusive starts, both batches
    const int tid  = threadIdx.x;
    const int lane = tid & 63;

    // waves 0,1: scan batch (wave index). 1000 cells = 64 lanes x 16 elems.
    if (tid < 128) {
        const int b = tid >> 6;
        int c16[16];
        int tot = 0;
        #pragma unroll
        for (int k = 0; k < 16; ++k) {
            const int i = lane * 16 + k;
            c16[k] = (i < NCELL) ? cnt[b * NCELL + i] : 0;
            tot += c16[k];
        }
        int ex = tot;
        #pragma unroll
        for (int off = 1; off < 64; off <<= 1) {
            const int u = __shfl_up(ex, off);
            if (lane >= off) ex += u;
        }
        ex -= tot;                       // exclusive prefix of lane totals
        int run = ex;
        #pragma unroll
        for (int k = 0; k < 16; ++k) {
            const int i = lane * 16 + k;
            if (i < NCELL) scs[b * NCELL + i] = run;
            run += c16[k];
        }
    }
    __syncthreads();

    // block 0: publish cstart to global for qg_grid
    if (blockIdx.x == 0) {
        for (int i = tid; i < 2 * (NCELL + 1); i += 256) {
            const int b  = i / (NCELL + 1);
            const int ci = i - b * (NCELL + 1);
            cstart[i] = (ci == NCELL) ? NPTS : scs[b * NCELL + ci];
        }
    }

    // scatter: one point per thread (128 blocks x 256 = 32768)
    const int g = blockIdx.x * 256 + tid;
    const int b = g >> 14;
    const int j = g & (NPTS - 1);
    const float x = xyz[g*3], y = xyz[g*3+1], z = xyz[g*3+2];
    const int c = cell_of(x, y, z);
    const int pos = atomicAdd(&fill[b * NCELL + c], 1);
    pxyzj[b * NPTS + scs[b * NCELL + c] + pos] =
        make_float4(x, y, z, __int_as_float(j));
}

// ---------------- main: grid-accelerated ball query + group ----------------
__global__ __launch_bounds__(256) void qg_grid(
    const float* __restrict__ xyz,      // (B, N, 3)
    const float* __restrict__ new_xyz,  // (B, P, 3)
    const float4* __restrict__ featT4,  // (B, N, C)
    const int* __restrict__ cstart,     // (B, NCELL+1)
    const float4* __restrict__ pxyzj,   // (B, N) sorted {x,y,z,j}
    float* __restrict__ out)            // (B, 67, P, S)
{
    const int wave = threadIdx.x >> 6;
    const int lane = threadIdx.x & 63;
    const int bp   = blockIdx.x * 4 + wave;
    const int b    = bp >> 12;
    const int p    = bp & (NQ - 1);

    __shared__ int hbuf[4][MAXHITS];
    __shared__ int idx_s[4][NS];

    const float qx = new_xyz[bp * 3 + 0];
    const float qy = new_xyz[bp * 3 + 1];
    const float qz = new_xyz[bp * 3 + 2];
    const float* xb = xyz + (size_t)b * NPTS * 3;
    const int* cs = cstart + b * (NCELL + 1);
    const float4* pb = pxyzj + (size_t)b * NPTS;

    int qcx = (int)(qx * GDIM); qcx = qcx < 0 ? 0 : (qcx > GDIM-1 ? GDIM-1 : qcx);
    int qcy = (int)(qy * GDIM); qcy = qcy < 0 ? 0 : (qcy > GDIM-1 ? GDIM-1 : qcy);
    int qcz = (int)(qz * GDIM); qcz = qcz < 0 ? 0 : (qcz > GDIM-1 ? GDIM-1 : qcz);
    const int x0 = qcx > 0 ? qcx - 1 : 0;
    const int x1 = qcx < GDIM-1 ? qcx + 1 : GDIM-1;
    const int y0 = qcy > 0 ? qcy - 1 : 0;
    const int y1 = qcy < GDIM-1 ? qcy + 1 : GDIM-1;
    const int z0 = qcz > 0 ? qcz - 1 : 0;
    const int z1 = qcz < GDIM-1 ? qcz + 1 : GDIM-1;

    const unsigned long long below = (1ull << lane) - 1ull;
    int hitcnt = 0;

    for (int gz = z0; gz <= z1; ++gz) {
        for (int gy = y0; gy <= y1; ++gy) {
            const int crow = (gz * GDIM + gy) * GDIM;
            const int s = cs[crow + x0];
            const int e = cs[crow + x1 + 1];
            for (int pos = s; pos < e; pos += 64) {
                const int i = pos + lane;
                const bool inr = i < e;
                const float4 pt = pb[inr ? i : 0];   // coalesced dwordx4
                const float dx = pt.x - qx;
                const float dy = pt.y - qy;
                const float dz = pt.z - qz;
                const bool hit = inr && (dx*dx + dy*dy + dz*dz < R2);
                const unsigned long long m = __ballot(hit);
                if (hit) {
                    const int slot = hitcnt + __popcll(m & below);
                    if (slot < MAXHITS) hbuf[wave][slot] = __float_as_int(pt.w);
                }
                hitcnt += __popcll(m);
            }
        }
    }
    __builtin_amdgcn_wave_barrier();

    // ---- select 32 smallest hit indices (== first 32 in index order) ----
    const int nh = hitcnt < MAXHITS ? hitcnt : MAXHITS;
    int v0 = (lane       < nh) ? hbuf[wave][lane      ] : INT_MAX;
    int v1 = (lane +  64 < nh) ? hbuf[wave][lane +  64] : INT_MAX;
    int v2 = (lane + 128 < nh) ? hbuf[wave][lane + 128] : INT_MAX;
    int v3 = (lane + 192 < nh) ? hbuf[wave][lane + 192] : INT_MAX;

    int sel = INT_MAX;
    #pragma unroll
    for (int k = 0; k < NS; ++k) {
        int m4 = min(min(v0, v1), min(v2, v3));
        #pragma unroll
        for (int off = 32; off > 0; off >>= 1)
            m4 = min(m4, __shfl_xor(m4, off));
        if (lane == k) sel = m4;
        v0 = (v0 == m4) ? INT_MAX : v0;
        v1 = (v1 == m4) ? INT_MAX : v1;
        v2 = (v2 == m4) ? INT_MAX : v2;
        v3 = (v3 == m4) ? INT_MAX : v3;
    }
    const int first = __shfl(sel, 0);
    if (lane < NS) {
        int v = sel;
        if (v == INT_MAX) v = (first == INT_MAX) ? 0 : first;
        idx_s[wave][lane] = v;
    }
    __builtin_amdgcn_wave_barrier();

    const size_t cstride = (size_t)NQ * NS;
    const size_t out_q   = ((size_t)b * COUT * NQ + (size_t)p) * NS;

    // xyz channels: lanes 0..31, contiguous 128-B stores
    if (lane < NS) {
        const int j = idx_s[wave][lane];
        out[out_q + 0*cstride + lane] = xb[j*3+0] - qx;
        out[out_q + 1*cstride + lane] = xb[j*3+1] - qy;
        out[out_q + 2*cstride + lane] = xb[j*3+2] - qz;
    }

    // feature channels: lane = (soff 0..3, cg 0..15), float4 gathers
    const int cg   = lane & 15;
    const int soff = lane >> 4;
    #pragma unroll
    for (int it = 0; it < 8; ++it) {
        const int s = it * 4 + soff;
        const int j = idx_s[wave][s];
        const float4 v = featT4[((size_t)b * NPTS + j) * 16 + cg];
        const size_t o = out_q + (size_t)(3 + cg * 4) * cstride + s;
        out[o              ] = v.x;
        out[o +     cstride] = v.y;
        out[o + 2 * cstride] = v.z;
        out[o + 3 * cstride] = v.w;
    }
}

// ---------------- fallback: linear-scan kernel ----------------
__global__ __launch_bounds__(256) void qg_linear(
    const float* __restrict__ xyz, const float* __restrict__ new_xyz,
    const float* __restrict__ feat, float* __restrict__ out)
{
    const int wave = threadIdx.x >> 6;
    const int lane = threadIdx.x & 63;
    const int bp   = blockIdx.x * 4 + wave;
    const int b    = bp >> 12;
    const int p    = bp & (NQ - 1);
    __shared__ int idx_s[4][NS];
    const float qx = new_xyz[bp*3+0], qy = new_xyz[bp*3+1], qz = new_xyz[bp*3+2];
    const float* xb = xyz + (size_t)b * NPTS * 3;
    int cnt = 0;
    const unsigned long long below = (1ull << lane) - 1ull;
    for (int base = 0; base < NPTS; base += 64) {
        const int j = base + lane;
        const float dx = xb[j*3+0]-qx, dy = xb[j*3+1]-qy, dz = xb[j*3+2]-qz;
        const bool hit = dx*dx+dy*dy+dz*dz < R2;
        const unsigned long long m = __ballot(hit);
        if (hit) {
            const int slot = cnt + __popcll(m & below);
            if (slot < NS) idx_s[wave][slot] = j;
        }
        cnt += __popcll(m);
        if (cnt >= NS) break;
    }
    __builtin_amdgcn_wave_barrier();
    if (cnt < NS) {
        const int first = (cnt > 0) ? idx_s[wave][0] : 0;
        if (lane >= cnt && lane < NS) idx_s[wave][lane] = first;
    }
    __builtin_amdgcn_wave_barrier();
    const size_t cstride = (size_t)NQ * NS;
    const size_t out_q = ((size_t)b * COUT * NQ + (size_t)p) * NS;
    if (lane < NS) {
        const int j = idx_s[wave][lane];
        out[out_q + 0*cstride + lane] = xb[j*3+0] - qx;
        out[out_q + 1*cstride + lane] = xb[j*3+1] - qy;
        out[out_q + 2*cstride + lane] = xb[j*3+2] - qz;
    }
    const float* fb = feat + (size_t)b * CFEAT * NPTS;
    const int s = lane & 31, half = lane >> 5;
    const int j = idx_s[wave][s];
    #pragma unroll 8
    for (int c = half; c < CFEAT; c += 2)
        out[out_q + (size_t)(3 + c) * cstride + s] = fb[(size_t)c * NPTS + j];
}

extern "C" void kernel_launch(void* const* d_in, const int* in_sizes, int n_in,
                              void* d_out, int out_size, void* d_ws, size_t ws_size,
                              hipStream_t stream) {
    const float* xyz     = (const float*)d_in[0];  // (2,16384,3)
    const float* new_xyz = (const float*)d_in[1];  // (2,4096,3)
    const float* feat    = (const float*)d_in[2];  // (2,64,16384)
    float* out = (float*)d_out;                    // (2,67,4096,32)

    const size_t need_full = FEATT_BYTES + PXYZJ_BYTES + (size_t)GRID_INTS * sizeof(int);

    if (ws_size >= need_full) {
        float*  featT = (float*)d_ws;
        float4* pxyzj = (float4*)((char*)d_ws + FEATT_BYTES);
        int* gi = (int*)((char*)d_ws + FEATT_BYTES + PXYZJ_BYTES);
        int* cnt    = gi + OFF_CNT;
        int* fill   = gi + OFF_FILL;
        int* cstart = gi + OFF_CSTART;

        hipMemsetAsync(cnt, 0, 4 * NCELL * sizeof(int), stream);  // cnt + fill
        prep1_kernel<<<512 + (BATCH * NPTS) / 256, 256, 0, stream>>>(feat, featT, xyz, cnt);
        prep2_kernel<<<(BATCH * NPTS) / 256, 256, 0, stream>>>(xyz, cnt, fill, cstart, pxyzj);
        qg_grid<<<(BATCH * NQ) / 4, 256, 0, stream>>>(
            xyz, new_xyz, (const float4*)featT, cstart, pxyzj, out);
    } else {
        qg_linear<<<(BATCH * NQ) / 4, 256, 0, stream>>>(xyz, new_xyz, feat, out);
    }
}

// Round 5
// 137.849 us; speedup vs baseline: 1.7172x; 1.0713x over previous
//
#include <hip/hip_runtime.h>
#include <hip/hip_bf16.h>
#include <climits>

#define BATCH   2
#define NPTS    16384   // N
#define NQ      4096    // P
#define CFEAT   64
#define NS      32      // nsample
#define R2      0.01f   // radius^2
#define COUT    (3 + CFEAT)   // 67
#define GDIM    10      // grid cells per axis (cell size = radius)
#define NCELL   (GDIM * GDIM * GDIM)
#define NWORDS  (NPTS / 32)   // 512 words per batch-slice bitmask

// ---- ws layout (bytes) ----
// [0, 8MB)        : featT  (B,N,C) float
// [8MB, +512KB)   : pxyzj  (B,N) float4 {x,y,z,bitcast(j)}  cell-sorted
// then ints       : cnt[2*NCELL] | fill[2*NCELL] | cstart[2*(NCELL+1)]
#define FEATT_BYTES ((size_t)BATCH * NPTS * CFEAT * sizeof(float))
#define PXYZJ_BYTES ((size_t)BATCH * NPTS * sizeof(float4))
#define OFF_CNT    0
#define OFF_FILL   (2 * NCELL)
#define OFF_CSTART (4 * NCELL)
#define GRID_INTS  (4 * NCELL + 2 * (NCELL + 1))

__device__ __forceinline__ int cell_of(float x, float y, float z) {
    int cx = (int)(x * GDIM); cx = cx < 0 ? 0 : (cx > GDIM - 1 ? GDIM - 1 : cx);
    int cy = (int)(y * GDIM); cy = cy < 0 ? 0 : (cy > GDIM - 1 ? GDIM - 1 : cy);
    int cz = (int)(z * GDIM); cz = cz < 0 ? 0 : (cz > GDIM - 1 ? GDIM - 1 : cz);
    return (cz * GDIM + cy) * GDIM + cx;   // x fastest -> contiguous x-runs
}

// ---------------- fused: transpose (blocks 0..511) + count (blocks 512..639) ----
__global__ __launch_bounds__(256) void prep1_kernel(
    const float* __restrict__ feat, float* __restrict__ featT,
    const float* __restrict__ xyz, int* __restrict__ cnt)
{
    __shared__ float tile[64][65];
    if (blockIdx.x < 512) {
        const int b    = blockIdx.x >> 8;
        const int n0   = (blockIdx.x & 255) * 64;
        const int lane = threadIdx.x & 63;
        const int grp  = threadIdx.x >> 6;           // 0..3
        const float* fb = feat + (size_t)b * CFEAT * NPTS;
        #pragma unroll
        for (int k = 0; k < 16; ++k) {
            const int c = grp * 16 + k;
            tile[c][lane] = fb[(size_t)c * NPTS + n0 + lane];
        }
        __syncthreads();
        float* db = featT + ((size_t)b * NPTS + n0) * CFEAT;
        #pragma unroll
        for (int k = 0; k < 16; ++k) {
            const int n = grp * 16 + k;
            db[(size_t)n * CFEAT + lane] = tile[lane][n];
        }
    } else {
        const int g = (blockIdx.x - 512) * 256 + threadIdx.x;   // 0..B*N-1
        const int b = g >> 14;
        const int c = cell_of(xyz[g*3], xyz[g*3+1], xyz[g*3+2]);
        atomicAdd(&cnt[b * NCELL + c], 1);
    }
}

// ---------------- scan (redundant per block, in LDS) + scatter ----------------
__global__ __launch_bounds__(256) void prep2_kernel(
    const float* __restrict__ xyz, const int* __restrict__ cnt,
    int* __restrict__ fill, int* __restrict__ cstart,
    float4* __restrict__ pxyzj)
{
    __shared__ int scs[2 * NCELL];       // exclusive starts, both batches
    const int tid  = threadIdx.x;
    const int lane = tid & 63;

    // waves 0,1: scan batch (wave index). 1000 cells = 64 lanes x 16 elems.
    if (tid < 128) {
        const int b = tid >> 6;
        int c16[16];
        int tot = 0;
        #pragma unroll
        for (int k = 0; k < 16; ++k) {
            const int i = lane * 16 + k;
            c16[k] = (i < NCELL) ? cnt[b * NCELL + i] : 0;
            tot += c16[k];
        }
        int ex = tot;
        #pragma unroll
        for (int off = 1; off < 64; off <<= 1) {
            const int u = __shfl_up(ex, off);
            if (lane >= off) ex += u;
        }
        ex -= tot;                       // exclusive prefix of lane totals
        int run = ex;
        #pragma unroll
        for (int k = 0; k < 16; ++k) {
            const int i = lane * 16 + k;
            if (i < NCELL) scs[b * NCELL + i] = run;
            run += c16[k];
        }
    }
    __syncthreads();

    // block 0: publish cstart to global for qg_grid
    if (blockIdx.x == 0) {
        for (int i = tid; i < 2 * (NCELL + 1); i += 256) {
            const int b  = i / (NCELL + 1);
            const int ci = i - b * (NCELL + 1);
            cstart[i] = (ci == NCELL) ? NPTS : scs[b * NCELL + ci];
        }
    }

    // scatter: one point per thread (128 blocks x 256 = 32768)
    const int g = blockIdx.x * 256 + tid;
    const int b = g >> 14;
    const int j = g & (NPTS - 1);
    const float x = xyz[g*3], y = xyz[g*3+1], z = xyz[g*3+2];
    const int c = cell_of(x, y, z);
    const int pos = atomicAdd(&fill[b * NCELL + c], 1);
    pxyzj[b * NPTS + scs[b * NCELL + c] + pos] =
        make_float4(x, y, z, __int_as_float(j));
}

// ---------------- main: grid-accelerated ball query + group ----------------
// Bitmask selection: hits set bit j in a 2KB/wave LDS bitmask; the first 32
// set bits (== first 32 in index order) are extracted with ONE prefix scan.
__global__ __launch_bounds__(256) void qg_grid(
    const float* __restrict__ xyz,      // (B, N, 3)
    const float* __restrict__ new_xyz,  // (B, P, 3)
    const float4* __restrict__ featT4,  // (B, N, C)
    const int* __restrict__ cstart,     // (B, NCELL+1)
    const float4* __restrict__ pxyzj,   // (B, N) sorted {x,y,z,j}
    float* __restrict__ out)            // (B, 67, P, S)
{
    const int wave = threadIdx.x >> 6;
    const int lane = threadIdx.x & 63;
    const int bp   = blockIdx.x * 4 + wave;
    const int b    = bp >> 12;
    const int p    = bp & (NQ - 1);

    __shared__ unsigned int hmask[4][NWORDS];   // 2KB per wave
    __shared__ int idx_s[4][NS];

    // zero this wave's bitmask: 512 words = 64 lanes x 2 uint4
    {
        uint4 z; z.x = 0; z.y = 0; z.z = 0; z.w = 0;
        ((uint4*)hmask[wave])[lane]      = z;
        ((uint4*)hmask[wave])[lane + 64] = z;
    }
    __builtin_amdgcn_wave_barrier();

    const float qx = new_xyz[bp * 3 + 0];
    const float qy = new_xyz[bp * 3 + 1];
    const float qz = new_xyz[bp * 3 + 2];
    const float* xb = xyz + (size_t)b * NPTS * 3;
    const int* cs = cstart + b * (NCELL + 1);
    const float4* pb = pxyzj + (size_t)b * NPTS;

    int qcx = (int)(qx * GDIM); qcx = qcx < 0 ? 0 : (qcx > GDIM-1 ? GDIM-1 : qcx);
    int qcy = (int)(qy * GDIM); qcy = qcy < 0 ? 0 : (qcy > GDIM-1 ? GDIM-1 : qcy);
    int qcz = (int)(qz * GDIM); qcz = qcz < 0 ? 0 : (qcz > GDIM-1 ? GDIM-1 : qcz);
    const int x0 = qcx > 0 ? qcx - 1 : 0;
    const int x1 = qcx < GDIM-1 ? qcx + 1 : GDIM-1;
    const int y0 = qcy > 0 ? qcy - 1 : 0;
    const int y1 = qcy < GDIM-1 ? qcy + 1 : GDIM-1;
    const int z0 = qcz > 0 ? qcz - 1 : 0;
    const int z1 = qcz < GDIM-1 ? qcz + 1 : GDIM-1;
    const int ny  = y1 - y0 + 1;                 // 2 or 3
    const int nyz = ny * (z1 - z0 + 1);          // up to 9

    // preload all run bounds in parallel (lanes 0..nyz-1)
    int sv = 0, ev = 0;
    if (lane < nyz) {
        const int gzi = (ny == 3) ? ((lane * 86) >> 8) : (lane >> 1);
        const int gyi = lane - gzi * ny;
        const int crow = ((z0 + gzi) * GDIM + (y0 + gyi)) * GDIM;
        sv = cs[crow + x0];
        ev = cs[crow + x1 + 1];
    }

    for (int r = 0; r < nyz; ++r) {
        const int s = __shfl(sv, r);
        const int e = __shfl(ev, r);
        for (int pos = s; pos < e; pos += 64) {
            const int i = pos + lane;
            const bool inr = i < e;
            const float4 pt = pb[inr ? i : 0];   // coalesced dwordx4
            const float dx = pt.x - qx;
            const float dy = pt.y - qy;
            const float dz = pt.z - qz;
            if (inr && (dx*dx + dy*dy + dz*dz < R2)) {
                const int j = __float_as_int(pt.w);
                atomicOr(&hmask[wave][j >> 5], 1u << (j & 31));
            }
        }
    }
    __builtin_amdgcn_wave_barrier();

    // ---- extract first NS set bits in index order ----
    // lane owns words [lane*8, lane*8+8)  (j range [lane*256, lane*256+256))
    unsigned int w[8];
    {
        const uint4 a = ((const uint4*)hmask[wave])[lane * 2];
        const uint4 c = ((const uint4*)hmask[wave])[lane * 2 + 1];
        w[0] = a.x; w[1] = a.y; w[2] = a.z; w[3] = a.w;
        w[4] = c.x; w[5] = c.y; w[6] = c.z; w[7] = c.w;
    }
    int cnt8 = 0;
    #pragma unroll
    for (int k = 0; k < 8; ++k) cnt8 += __popc(w[k]);

    int pfx = cnt8;
    #pragma unroll
    for (int off = 1; off < 64; off <<= 1) {
        const int u = __shfl_up(pfx, off);
        if (lane >= off) pfx += u;
    }
    const int K = __shfl(pfx, 63);   // total hits
    pfx -= cnt8;                     // exclusive prefix (this lane's base rank)

    if (pfx < NS && cnt8 > 0) {
        int r = pfx;
        #pragma unroll
        for (int k = 0; k < 8; ++k) {
            unsigned int m = w[k];
            while (m && r < NS) {
                const int bit = __builtin_ctz(m);
                idx_s[wave][r] = lane * 256 + k * 32 + bit;
                m &= m - 1;
                ++r;
            }
        }
    }
    __builtin_amdgcn_wave_barrier();

    if (lane < NS && lane >= K) {
        idx_s[wave][lane] = (K > 0) ? idx_s[wave][0] : 0;
    }
    __builtin_amdgcn_wave_barrier();

    const size_t cstride = (size_t)NQ * NS;
    const size_t out_q   = ((size_t)b * COUT * NQ + (size_t)p) * NS;

    // xyz channels: lanes 0..31, contiguous 128-B stores
    if (lane < NS) {
        const int j = idx_s[wave][lane];
        out[out_q + 0*cstride + lane] = xb[j*3+0] - qx;
        out[out_q + 1*cstride + lane] = xb[j*3+1] - qy;
        out[out_q + 2*cstride + lane] = xb[j*3+2] - qz;
    }

    // feature channels: lane = (soff 0..3, cg 0..15), float4 gathers
    const int cg   = lane & 15;
    const int soff = lane >> 4;
    #pragma unroll
    for (int it = 0; it < 8; ++it) {
        const int s = it * 4 + soff;
        const int j = idx_s[wave][s];
        const float4 v = featT4[((size_t)b * NPTS + j) * 16 + cg];
        const size_t o = out_q + (size_t)(3 + cg * 4) * cstride + s;
        out[o              ] = v.x;
        out[o +     cstride] = v.y;
        out[o + 2 * cstride] = v.z;
        out[o + 3 * cstride] = v.w;
    }
}

// ---------------- fallback: linear-scan kernel ----------------
__global__ __launch_bounds__(256) void qg_linear(
    const float* __restrict__ xyz, const float* __restrict__ new_xyz,
    const float* __restrict__ feat, float* __restrict__ out)
{
    const int wave = threadIdx.x >> 6;
    const int lane = threadIdx.x & 63;
    const int bp   = blockIdx.x * 4 + wave;
    const int b    = bp >> 12;
    const int p    = bp & (NQ - 1);
    __shared__ int idx_s[4][NS];
    const float qx = new_xyz[bp*3+0], qy = new_xyz[bp*3+1], qz = new_xyz[bp*3+2];
    const float* xb = xyz + (size_t)b * NPTS * 3;
    int cnt = 0;
    const unsigned long long below = (1ull << lane) - 1ull;
    for (int base = 0; base < NPTS; base += 64) {
        const int j = base + lane;
        const float dx = xb[j*3+0]-qx, dy = xb[j*3+1]-qy, dz = xb[j*3+2]-qz;
        const bool hit = dx*dx+dy*dy+dz*dz < R2;
        const unsigned long long m = __ballot(hit);
        if (hit) {
            const int slot = cnt + __popcll(m & below);
            if (slot < NS) idx_s[wave][slot] = j;
        }
        cnt += __popcll(m);
        if (cnt >= NS) break;
    }
    __builtin_amdgcn_wave_barrier();
    if (cnt < NS) {
        const int first = (cnt > 0) ? idx_s[wave][0] : 0;
        if (lane >= cnt && lane < NS) idx_s[wave][lane] = first;
    }
    __builtin_amdgcn_wave_barrier();
    const size_t cstride = (size_t)NQ * NS;
    const size_t out_q = ((size_t)b * COUT * NQ + (size_t)p) * NS;
    if (lane < NS) {
        const int j = idx_s[wave][lane];
        out[out_q + 0*cstride + lane] = xb[j*3+0] - qx;
        out[out_q + 1*cstride + lane] = xb[j*3+1] - qy;
        out[out_q + 2*cstride + lane] = xb[j*3+2] - qz;
    }
    const float* fb = feat + (size_t)b * CFEAT * NPTS;
    const int s = lane & 31, half = lane >> 5;
    const int j = idx_s[wave][s];
    #pragma unroll 8
    for (int c = half; c < CFEAT; c += 2)
        out[out_q + (size_t)(3 + c) * cstride + s] = fb[(size_t)c * NPTS + j];
}

extern "C" void kernel_launch(void* const* d_in, const int* in_sizes, int n_in,
                              void* d_out, int out_size, void* d_ws, size_t ws_size,
                              hipStream_t stream) {
    const float* xyz     = (const float*)d_in[0];  // (2,16384,3)
    const float* new_xyz = (const float*)d_in[1];  // (2,4096,3)
    const float* feat    = (const float*)d_in[2];  // (2,64,16384)
    float* out = (float*)d_out;                    // (2,67,4096,32)

    const size_t need_full = FEATT_BYTES + PXYZJ_BYTES + (size_t)GRID_INTS * sizeof(int);

    if (ws_size >= need_full) {
        float*  featT = (float*)d_ws;
        float4* pxyzj = (float4*)((char*)d_ws + FEATT_BYTES);
        int* gi = (int*)((char*)d_ws + FEATT_BYTES + PXYZJ_BYTES);
        int* cnt    = gi + OFF_CNT;
        int* fill   = gi + OFF_FILL;
        int* cstart = gi + OFF_CSTART;

        hipMemsetAsync(cnt, 0, 4 * NCELL * sizeof(int), stream);  // cnt + fill
        prep1_kernel<<<512 + (BATCH * NPTS) / 256, 256, 0, stream>>>(feat, featT, xyz, cnt);
        prep2_kernel<<<(BATCH * NPTS) / 256, 256, 0, stream>>>(xyz, cnt, fill, cstart, pxyzj);
        qg_grid<<<(BATCH * NQ) / 4, 256, 0, stream>>>(
            xyz, new_xyz, (const float4*)featT, cstart, pxyzj, out);
    } else {
        qg_linear<<<(BATCH * NQ) / 4, 256, 0, stream>>>(xyz, new_xyz, feat, out);
    }
}

// Round 6
// 122.986 us; speedup vs baseline: 1.9247x; 1.1208x over previous
//
#include <hip/hip_runtime.h>
#include <hip/hip_bf16.h>
#include <climits>

#define BATCH   2
#define NPTS    16384   // N
#define NQ      4096    // P
#define CFEAT   64
#define NS      32      // nsample
#define R2      0.01f   // radius^2
#define COUT    (3 + CFEAT)   // 67
#define GDIM    10      // grid cells per axis (cell size = radius)
#define NCELL   (GDIM * GDIM * GDIM)
#define NWORDS  (NPTS / 32)   // 512 words per bitmask

// ---- ws layout (bytes) ----
// [0, 8MB)     : featT  (B,N,C) float
// +512KB       : pxyzj  (B,N) float4 {x,y,z,bitcast(j)} cell-sorted
// +1MB         : idx    (B,P,NS) int
// then ints    : cnt[2*NCELL] | fill[2*NCELL] | cstart[2*(NCELL+1)]
#define FEATT_BYTES ((size_t)BATCH * NPTS * CFEAT * sizeof(float))
#define PXYZJ_BYTES ((size_t)BATCH * NPTS * sizeof(float4))
#define IDX_BYTES   ((size_t)BATCH * NQ * NS * sizeof(int))
#define OFF_CNT    0
#define OFF_FILL   (2 * NCELL)
#define OFF_CSTART (4 * NCELL)
#define GRID_INTS  (4 * NCELL + 2 * (NCELL + 1))

__device__ __forceinline__ int cell_of(float x, float y, float z) {
    int cx = (int)(x * GDIM); cx = cx < 0 ? 0 : (cx > GDIM - 1 ? GDIM - 1 : cx);
    int cy = (int)(y * GDIM); cy = cy < 0 ? 0 : (cy > GDIM - 1 ? GDIM - 1 : cy);
    int cz = (int)(z * GDIM); cz = cz < 0 ? 0 : (cz > GDIM - 1 ? GDIM - 1 : cz);
    return (cz * GDIM + cy) * GDIM + cx;   // x fastest -> contiguous x-runs
}

// ---------------- fused: transpose (blocks 0..511) + count (blocks 512..639) ----
__global__ __launch_bounds__(256) void prep1_kernel(
    const float* __restrict__ feat, float* __restrict__ featT,
    const float* __restrict__ xyz, int* __restrict__ cnt)
{
    __shared__ float tile[64][65];
    if (blockIdx.x < 512) {
        const int b    = blockIdx.x >> 8;
        const int n0   = (blockIdx.x & 255) * 64;
        const int lane = threadIdx.x & 63;
        const int grp  = threadIdx.x >> 6;           // 0..3
        const float* fb = feat + (size_t)b * CFEAT * NPTS;
        #pragma unroll
        for (int k = 0; k < 16; ++k) {
            const int c = grp * 16 + k;
            tile[c][lane] = fb[(size_t)c * NPTS + n0 + lane];
        }
        __syncthreads();
        float* db = featT + ((size_t)b * NPTS + n0) * CFEAT;
        #pragma unroll
        for (int k = 0; k < 16; ++k) {
            const int n = grp * 16 + k;
            db[(size_t)n * CFEAT + lane] = tile[lane][n];
        }
    } else {
        const int g = (blockIdx.x - 512) * 256 + threadIdx.x;   // 0..B*N-1
        const int b = g >> 14;
        const int c = cell_of(xyz[g*3], xyz[g*3+1], xyz[g*3+2]);
        atomicAdd(&cnt[b * NCELL + c], 1);
    }
}

// ---------------- scan (redundant per block, in LDS) + scatter ----------------
__global__ __launch_bounds__(256) void prep2_kernel(
    const float* __restrict__ xyz, const int* __restrict__ cnt,
    int* __restrict__ fill, int* __restrict__ cstart,
    float4* __restrict__ pxyzj)
{
    __shared__ int scs[2 * NCELL];       // exclusive starts, both batches
    const int tid  = threadIdx.x;
    const int lane = tid & 63;

    if (tid < 128) {
        const int b = tid >> 6;
        int c16[16];
        int tot = 0;
        #pragma unroll
        for (int k = 0; k < 16; ++k) {
            const int i = lane * 16 + k;
            c16[k] = (i < NCELL) ? cnt[b * NCELL + i] : 0;
            tot += c16[k];
        }
        int ex = tot;
        #pragma unroll
        for (int off = 1; off < 64; off <<= 1) {
            const int u = __shfl_up(ex, off);
            if (lane >= off) ex += u;
        }
        ex -= tot;
        int run = ex;
        #pragma unroll
        for (int k = 0; k < 16; ++k) {
            const int i = lane * 16 + k;
            if (i < NCELL) scs[b * NCELL + i] = run;
            run += c16[k];
        }
    }
    __syncthreads();

    if (blockIdx.x == 0) {
        for (int i = tid; i < 2 * (NCELL + 1); i += 256) {
            const int b  = i / (NCELL + 1);
            const int ci = i - b * (NCELL + 1);
            cstart[i] = (ci == NCELL) ? NPTS : scs[b * NCELL + ci];
        }
    }

    const int g = blockIdx.x * 256 + tid;
    const int b = g >> 14;
    const int j = g & (NPTS - 1);
    const float x = xyz[g*3], y = xyz[g*3+1], z = xyz[g*3+2];
    const int c = cell_of(x, y, z);
    const int pos = atomicAdd(&fill[b * NCELL + c], 1);
    pxyzj[b * NPTS + scs[b * NCELL + c] + pos] =
        make_float4(x, y, z, __int_as_float(j));
}

// ---------------- A: ball query, one 256-thread block per query ----------------
// 4 waves share the scan (block-level bitmask via atomicOr); wave 0 extracts
// the first NS set bits with one prefix scan, writes idx + the 3 xyz channels.
__global__ __launch_bounds__(256) void qg_query(
    const float* __restrict__ xyz,      // (B, N, 3)
    const float* __restrict__ new_xyz,  // (B, P, 3)
    const int* __restrict__ cstart,     // (B, NCELL+1)
    const float4* __restrict__ pxyzj,   // (B, N) sorted {x,y,z,j}
    int* __restrict__ idx_out,          // (B, P, NS)
    float* __restrict__ out)            // (B, 67, P, S)
{
    const int q    = blockIdx.x;        // 0..B*P-1
    const int b    = q >> 12;
    const int p    = q & (NQ - 1);
    const int tid  = threadIdx.x;
    const int wave = tid >> 6;
    const int lane = tid & 63;

    __shared__ unsigned int hmask[NWORDS];   // 2KB block-shared bitmask
    __shared__ int idx_s[NS];

    if (tid < 128) {
        uint4 z; z.x = 0; z.y = 0; z.z = 0; z.w = 0;
        ((uint4*)hmask)[tid] = z;
    }

    const float qx = new_xyz[q * 3 + 0];
    const float qy = new_xyz[q * 3 + 1];
    const float qz = new_xyz[q * 3 + 2];
    const float* xb = xyz + (size_t)b * NPTS * 3;
    const int* cs = cstart + b * (NCELL + 1);
    const float4* pb = pxyzj + (size_t)b * NPTS;

    int qcx = (int)(qx * GDIM); qcx = qcx < 0 ? 0 : (qcx > GDIM-1 ? GDIM-1 : qcx);
    int qcy = (int)(qy * GDIM); qcy = qcy < 0 ? 0 : (qcy > GDIM-1 ? GDIM-1 : qcy);
    int qcz = (int)(qz * GDIM); qcz = qcz < 0 ? 0 : (qcz > GDIM-1 ? GDIM-1 : qcz);
    const int x0 = qcx > 0 ? qcx - 1 : 0;
    const int x1 = qcx < GDIM-1 ? qcx + 1 : GDIM-1;
    const int y0 = qcy > 0 ? qcy - 1 : 0;
    const int y1 = qcy < GDIM-1 ? qcy + 1 : GDIM-1;
    const int z0 = qcz > 0 ? qcz - 1 : 0;
    const int z1 = qcz < GDIM-1 ? qcz + 1 : GDIM-1;
    const int ny  = y1 - y0 + 1;                 // 2 or 3
    const int nyz = ny * (z1 - z0 + 1);          // up to 9

    // each wave loads all run bounds (lanes 0..nyz-1), shfl-broadcast below
    int sv = 0, ev = 0;
    if (lane < nyz) {
        const int gzi = (ny == 3) ? ((lane * 86) >> 8) : (lane >> 1);
        const int gyi = lane - gzi * ny;
        const int crow = ((z0 + gzi) * GDIM + (y0 + gyi)) * GDIM;
        sv = cs[crow + x0];
        ev = cs[crow + x1 + 1];
    }
    __syncthreads();   // bitmask zeroed

    for (int r = wave; r < nyz; r += 4) {
        const int s = __shfl(sv, r);
        const int e = __shfl(ev, r);
        for (int pos = s; pos < e; pos += 64) {
            const int i = pos + lane;
            const bool inr = i < e;
            const float4 pt = pb[inr ? i : 0];   // coalesced dwordx4
            const float dx = pt.x - qx;
            const float dy = pt.y - qy;
            const float dz = pt.z - qz;
            if (inr && (dx*dx + dy*dy + dz*dz < R2)) {
                const int j = __float_as_int(pt.w);
                atomicOr(&hmask[j >> 5], 1u << (j & 31));
            }
        }
    }
    __syncthreads();   // all hits in bitmask

    if (wave == 0) {
        unsigned int w[8];
        {
            const uint4 a = ((const uint4*)hmask)[lane * 2];
            const uint4 c = ((const uint4*)hmask)[lane * 2 + 1];
            w[0] = a.x; w[1] = a.y; w[2] = a.z; w[3] = a.w;
            w[4] = c.x; w[5] = c.y; w[6] = c.z; w[7] = c.w;
        }
        int cnt8 = 0;
        #pragma unroll
        for (int k = 0; k < 8; ++k) cnt8 += __popc(w[k]);

        int pfx = cnt8;
        #pragma unroll
        for (int off = 1; off < 64; off <<= 1) {
            const int u = __shfl_up(pfx, off);
            if (lane >= off) pfx += u;
        }
        const int K = __shfl(pfx, 63);
        pfx -= cnt8;

        if (pfx < NS && cnt8 > 0) {
            int r = pfx;
            #pragma unroll
            for (int k = 0; k < 8; ++k) {
                unsigned int m = w[k];
                while (m && r < NS) {
                    const int bit = __builtin_ctz(m);
                    idx_s[r] = lane * 256 + k * 32 + bit;
                    m &= m - 1;
                    ++r;
                }
            }
        }
        __builtin_amdgcn_wave_barrier();
        if (lane < NS && lane >= K) {
            idx_s[lane] = (K > 0) ? idx_s[0] : 0;
        }
        __builtin_amdgcn_wave_barrier();

        if (lane < NS) {
            const int j = idx_s[lane];
            idx_out[q * NS + lane] = j;
            const size_t cstride = (size_t)NQ * NS;
            const size_t out_q   = ((size_t)b * COUT * NQ + (size_t)p) * NS;
            out[out_q + 0*cstride + lane] = xb[j*3+0] - qx;
            out[out_q + 1*cstride + lane] = xb[j*3+1] - qy;
            out[out_q + 2*cstride + lane] = xb[j*3+2] - qz;
        }
    }
}

// ---------------- B: group features, one 256-thread block per query ----------
// LDS-transpose so both gather loads (8x128B segs/inst) and output stores
// (2x128B contiguous segs/inst) are coalesced.
__global__ __launch_bounds__(256) void qg_group(
    const float4* __restrict__ featT4,  // (B, N, C)
    const int* __restrict__ idx_in,     // (B, P, NS)
    float* __restrict__ out)            // (B, 67, P, S)
{
    const int q   = blockIdx.x;
    const int b   = q >> 12;
    const int p   = q & (NQ - 1);
    const int tid = threadIdx.x;

    __shared__ float tile[NS][65];      // [sample][channel], +1 pad
    __shared__ int sj[NS];

    if (tid < NS) sj[tid] = idx_in[q * NS + tid];
    __syncthreads();

    // gather: thread (sm = tid>>3, q8 = tid&7) loads 2 float4 of row sm
    const int sm = tid >> 3;
    const int q8 = tid & 7;
    const float4* base = featT4 + ((size_t)b * NPTS + sj[sm]) * 16;
    const float4 v0 = base[q8];
    const float4 v1 = base[8 + q8];
    ((float4*)&tile[sm][q8 * 4])[0]      = v0;   // ds_write_b128
    ((float4*)&tile[sm][32 + q8 * 4])[0] = v1;
    __syncthreads();

    // store: thread (s = tid&31, c8 = tid>>5) writes 8 channels
    const int s  = tid & 31;
    const int c8 = tid >> 5;
    const size_t cstride = (size_t)NQ * NS;
    float* ob = out + ((size_t)b * COUT * NQ + (size_t)p) * NS + s + 3 * cstride;
    #pragma unroll
    for (int k = 0; k < 8; ++k) {
        const int c = c8 + k * 8;
        ob[(size_t)c * cstride] = tile[s][c];
    }
}

// ---------------- fallback: linear-scan kernel ----------------
__global__ __launch_bounds__(256) void qg_linear(
    const float* __restrict__ xyz, const float* __restrict__ new_xyz,
    const float* __restrict__ feat, float* __restrict__ out)
{
    const int wave = threadIdx.x >> 6;
    const int lane = threadIdx.x & 63;
    const int bp   = blockIdx.x * 4 + wave;
    const int b    = bp >> 12;
    const int p    = bp & (NQ - 1);
    __shared__ int idx_s[4][NS];
    const float qx = new_xyz[bp*3+0], qy = new_xyz[bp*3+1], qz = new_xyz[bp*3+2];
    const float* xb = xyz + (size_t)b * NPTS * 3;
    int cnt = 0;
    const unsigned long long below = (1ull << lane) - 1ull;
    for (int base = 0; base < NPTS; base += 64) {
        const int j = base + lane;
        const float dx = xb[j*3+0]-qx, dy = xb[j*3+1]-qy, dz = xb[j*3+2]-qz;
        const bool hit = dx*dx+dy*dy+dz*dz < R2;
        const unsigned long long m = __ballot(hit);
        if (hit) {
            const int slot = cnt + __popcll(m & below);
            if (slot < NS) idx_s[wave][slot] = j;
        }
        cnt += __popcll(m);
        if (cnt >= NS) break;
    }
    __builtin_amdgcn_wave_barrier();
    if (cnt < NS) {
        const int first = (cnt > 0) ? idx_s[wave][0] : 0;
        if (lane >= cnt && lane < NS) idx_s[wave][lane] = first;
    }
    __builtin_amdgcn_wave_barrier();
    const size_t cstride = (size_t)NQ * NS;
    const size_t out_q = ((size_t)b * COUT * NQ + (size_t)p) * NS;
    if (lane < NS) {
        const int j = idx_s[wave][lane];
        out[out_q + 0*cstride + lane] = xb[j*3+0] - qx;
        out[out_q + 1*cstride + lane] = xb[j*3+1] - qy;
        out[out_q + 2*cstride + lane] = xb[j*3+2] - qz;
    }
    const float* fb = feat + (size_t)b * CFEAT * NPTS;
    const int s = lane & 31, half = lane >> 5;
    const int j = idx_s[wave][s];
    #pragma unroll 8
    for (int c = half; c < CFEAT; c += 2)
        out[out_q + (size_t)(3 + c) * cstride + s] = fb[(size_t)c * NPTS + j];
}

extern "C" void kernel_launch(void* const* d_in, const int* in_sizes, int n_in,
                              void* d_out, int out_size, void* d_ws, size_t ws_size,
                              hipStream_t stream) {
    const float* xyz     = (const float*)d_in[0];  // (2,16384,3)
    const float* new_xyz = (const float*)d_in[1];  // (2,4096,3)
    const float* feat    = (const float*)d_in[2];  // (2,64,16384)
    float* out = (float*)d_out;                    // (2,67,4096,32)

    const size_t need_full = FEATT_BYTES + PXYZJ_BYTES + IDX_BYTES
                           + (size_t)GRID_INTS * sizeof(int);

    if (ws_size >= need_full) {
        float*  featT = (float*)d_ws;
        float4* pxyzj = (float4*)((char*)d_ws + FEATT_BYTES);
        int*    idx   = (int*)((char*)d_ws + FEATT_BYTES + PXYZJ_BYTES);
        int* gi = (int*)((char*)d_ws + FEATT_BYTES + PXYZJ_BYTES + IDX_BYTES);
        int* cnt    = gi + OFF_CNT;
        int* fill   = gi + OFF_FILL;
        int* cstart = gi + OFF_CSTART;

        hipMemsetAsync(cnt, 0, 4 * NCELL * sizeof(int), stream);  // cnt + fill
        prep1_kernel<<<512 + (BATCH * NPTS) / 256, 256, 0, stream>>>(feat, featT, xyz, cnt);
        prep2_kernel<<<(BATCH * NPTS) / 256, 256, 0, stream>>>(xyz, cnt, fill, cstart, pxyzj);
        qg_query<<<BATCH * NQ, 256, 0, stream>>>(xyz, new_xyz, cstart, pxyzj, idx, out);
        qg_group<<<BATCH * NQ, 256, 0, stream>>>((const float4*)featT, idx, out);
    } else {
        qg_linear<<<(BATCH * NQ) / 4, 256, 0, stream>>>(xyz, new_xyz, feat, out);
    }
}

// Round 7
// 119.725 us; speedup vs baseline: 1.9772x; 1.0272x over previous
//
#include <hip/hip_runtime.h>
#include <hip/hip_bf16.h>
#include <climits>

#define BATCH   2
#define NPTS    16384   // N
#define NQ      4096    // P
#define CFEAT   64
#define NS      32      // nsample
#define R2      0.01f   // radius^2
#define COUT    (3 + CFEAT)   // 67
#define GDIM    10      // grid cells per axis (cell size = radius)
#define NCELL   (GDIM * GDIM * GDIM)
#define NWORDS  (NPTS / 32)   // 512 words per bitmask

// ---- ws layout (bytes) ----
// [0, 8MB)     : featT  (B,N,C) float
// +512KB       : pxyzj  (B,N) float4 {x,y,z,bitcast(j)} cell-sorted
// then ints    : cnt[2*NCELL] | fill[2*NCELL] | cstart[2*(NCELL+1)]
#define FEATT_BYTES ((size_t)BATCH * NPTS * CFEAT * sizeof(float))
#define PXYZJ_BYTES ((size_t)BATCH * NPTS * sizeof(float4))
#define OFF_CNT    0
#define OFF_FILL   (2 * NCELL)
#define OFF_CSTART (4 * NCELL)
#define GRID_INTS  (4 * NCELL + 2 * (NCELL + 1))

__device__ __forceinline__ int cell_of(float x, float y, float z) {
    int cx = (int)(x * GDIM); cx = cx < 0 ? 0 : (cx > GDIM - 1 ? GDIM - 1 : cx);
    int cy = (int)(y * GDIM); cy = cy < 0 ? 0 : (cy > GDIM - 1 ? GDIM - 1 : cy);
    int cz = (int)(z * GDIM); cz = cz < 0 ? 0 : (cz > GDIM - 1 ? GDIM - 1 : cz);
    return (cz * GDIM + cy) * GDIM + cx;   // x fastest -> contiguous x-runs
}

// ---------------- fused: transpose (blocks 0..511) + count (blocks 512..639) ----
__global__ __launch_bounds__(256) void prep1_kernel(
    const float* __restrict__ feat, float* __restrict__ featT,
    const float* __restrict__ xyz, int* __restrict__ cnt)
{
    __shared__ float tile[64][65];
    if (blockIdx.x < 512) {
        const int b    = blockIdx.x >> 8;
        const int n0   = (blockIdx.x & 255) * 64;
        const int lane = threadIdx.x & 63;
        const int grp  = threadIdx.x >> 6;           // 0..3
        const float* fb = feat + (size_t)b * CFEAT * NPTS;
        #pragma unroll
        for (int k = 0; k < 16; ++k) {
            const int c = grp * 16 + k;
            tile[c][lane] = fb[(size_t)c * NPTS + n0 + lane];
        }
        __syncthreads();
        float* db = featT + ((size_t)b * NPTS + n0) * CFEAT;
        #pragma unroll
        for (int k = 0; k < 16; ++k) {
            const int n = grp * 16 + k;
            db[(size_t)n * CFEAT + lane] = tile[lane][n];
        }
    } else {
        const int g = (blockIdx.x - 512) * 256 + threadIdx.x;   // 0..B*N-1
        const int b = g >> 14;
        const int c = cell_of(xyz[g*3], xyz[g*3+1], xyz[g*3+2]);
        atomicAdd(&cnt[b * NCELL + c], 1);
    }
}

// ---------------- scan (redundant per block, in LDS) + scatter ----------------
__global__ __launch_bounds__(256) void prep2_kernel(
    const float* __restrict__ xyz, const int* __restrict__ cnt,
    int* __restrict__ fill, int* __restrict__ cstart,
    float4* __restrict__ pxyzj)
{
    __shared__ int scs[2 * NCELL];       // exclusive starts, both batches
    const int tid  = threadIdx.x;
    const int lane = tid & 63;

    if (tid < 128) {
        const int b = tid >> 6;
        int c16[16];
        int tot = 0;
        #pragma unroll
        for (int k = 0; k < 16; ++k) {
            const int i = lane * 16 + k;
            c16[k] = (i < NCELL) ? cnt[b * NCELL + i] : 0;
            tot += c16[k];
        }
        int ex = tot;
        #pragma unroll
        for (int off = 1; off < 64; off <<= 1) {
            const int u = __shfl_up(ex, off);
            if (lane >= off) ex += u;
        }
        ex -= tot;
        int run = ex;
        #pragma unroll
        for (int k = 0; k < 16; ++k) {
            const int i = lane * 16 + k;
            if (i < NCELL) scs[b * NCELL + i] = run;
            run += c16[k];
        }
    }
    __syncthreads();

    if (blockIdx.x == 0) {
        for (int i = tid; i < 2 * (NCELL + 1); i += 256) {
            const int b  = i / (NCELL + 1);
            const int ci = i - b * (NCELL + 1);
            cstart[i] = (ci == NCELL) ? NPTS : scs[b * NCELL + ci];
        }
    }

    const int g = blockIdx.x * 256 + tid;
    const int b = g >> 14;
    const int j = g & (NPTS - 1);
    const float x = xyz[g*3], y = xyz[g*3+1], z = xyz[g*3+2];
    const int c = cell_of(x, y, z);
    const int pos = atomicAdd(&fill[b * NCELL + c], 1);
    pxyzj[b * NPTS + scs[b * NCELL + c] + pos] =
        make_float4(x, y, z, __int_as_float(j));
}

// ---------------- fused main: one 256-thread block per query ----------------
// Phase 1: 4 waves scan candidate cell runs into a block bitmask (atomicOr);
//          wave 0 extracts first NS set bits with one prefix scan.
// Phase 2: gather 32 featT rows through an LDS tile; coalesced stores.
__global__ __launch_bounds__(256) void qg_fused(
    const float* __restrict__ xyz,      // (B, N, 3)
    const float* __restrict__ new_xyz,  // (B, P, 3)
    const int* __restrict__ cstart,     // (B, NCELL+1)
    const float4* __restrict__ pxyzj,   // (B, N) sorted {x,y,z,j}
    const float4* __restrict__ featT4,  // (B, N, C)
    float* __restrict__ out)            // (B, 67, P, S)
{
    const int q    = blockIdx.x;        // 0..B*P-1
    const int b    = q >> 12;
    const int p    = q & (NQ - 1);
    const int tid  = threadIdx.x;
    const int wave = tid >> 6;
    const int lane = tid & 63;

    __shared__ unsigned int hmask[NWORDS];   // 2KB block bitmask
    __shared__ int idx_s[NS];
    __shared__ float tile[NS][65];           // [sample][channel], +1 pad

    if (tid < 128) {
        uint4 z; z.x = 0; z.y = 0; z.z = 0; z.w = 0;
        ((uint4*)hmask)[tid] = z;
    }

    const float qx = new_xyz[q * 3 + 0];
    const float qy = new_xyz[q * 3 + 1];
    const float qz = new_xyz[q * 3 + 2];
    const float* xb = xyz + (size_t)b * NPTS * 3;
    const int* cs = cstart + b * (NCELL + 1);
    const float4* pb = pxyzj + (size_t)b * NPTS;

    int qcx = (int)(qx * GDIM); qcx = qcx < 0 ? 0 : (qcx > GDIM-1 ? GDIM-1 : qcx);
    int qcy = (int)(qy * GDIM); qcy = qcy < 0 ? 0 : (qcy > GDIM-1 ? GDIM-1 : qcy);
    int qcz = (int)(qz * GDIM); qcz = qcz < 0 ? 0 : (qcz > GDIM-1 ? GDIM-1 : qcz);
    const int x0 = qcx > 0 ? qcx - 1 : 0;
    const int x1 = qcx < GDIM-1 ? qcx + 1 : GDIM-1;
    const int y0 = qcy > 0 ? qcy - 1 : 0;
    const int y1 = qcy < GDIM-1 ? qcy + 1 : GDIM-1;
    const int z0 = qcz > 0 ? qcz - 1 : 0;
    const int z1 = qcz < GDIM-1 ? qcz + 1 : GDIM-1;
    const int ny  = y1 - y0 + 1;                 // 2 or 3
    const int nyz = ny * (z1 - z0 + 1);          // up to 9

    // each wave loads all run bounds (lanes 0..nyz-1), shfl-broadcast below
    int sv = 0, ev = 0;
    if (lane < nyz) {
        const int gzi = (ny == 3) ? ((lane * 86) >> 8) : (lane >> 1);
        const int gyi = lane - gzi * ny;
        const int crow = ((z0 + gzi) * GDIM + (y0 + gyi)) * GDIM;
        sv = cs[crow + x0];
        ev = cs[crow + x1 + 1];
    }
    __syncthreads();   // bitmask zeroed

    for (int r = wave; r < nyz; r += 4) {
        const int s = __shfl(sv, r);
        const int e = __shfl(ev, r);
        for (int pos = s; pos < e; pos += 64) {
            const int i = pos + lane;
            const bool inr = i < e;
            const float4 pt = pb[inr ? i : 0];   // coalesced dwordx4
            const float dx = pt.x - qx;
            const float dy = pt.y - qy;
            const float dz = pt.z - qz;
            if (inr && (dx*dx + dy*dy + dz*dz < R2)) {
                const int j = __float_as_int(pt.w);
                atomicOr(&hmask[j >> 5], 1u << (j & 31));
            }
        }
    }
    __syncthreads();   // all hits in bitmask

    // ---- extraction (wave 0 only): first NS set bits in index order ----
    if (wave == 0) {
        unsigned int w[8];
        {
            const uint4 a = ((const uint4*)hmask)[lane * 2];
            const uint4 c = ((const uint4*)hmask)[lane * 2 + 1];
            w[0] = a.x; w[1] = a.y; w[2] = a.z; w[3] = a.w;
            w[4] = c.x; w[5] = c.y; w[6] = c.z; w[7] = c.w;
        }
        int cnt8 = 0;
        #pragma unroll
        for (int k = 0; k < 8; ++k) cnt8 += __popc(w[k]);

        int pfx = cnt8;
        #pragma unroll
        for (int off = 1; off < 64; off <<= 1) {
            const int u = __shfl_up(pfx, off);
            if (lane >= off) pfx += u;
        }
        const int K = __shfl(pfx, 63);
        pfx -= cnt8;

        if (pfx < NS && cnt8 > 0) {
            int r = pfx;
            #pragma unroll
            for (int k = 0; k < 8; ++k) {
                unsigned int m = w[k];
                while (m && r < NS) {
                    const int bit = __builtin_ctz(m);
                    idx_s[r] = lane * 256 + k * 32 + bit;
                    m &= m - 1;
                    ++r;
                }
            }
        }
        __builtin_amdgcn_wave_barrier();
        if (lane < NS && lane >= K) {
            idx_s[lane] = (K > 0) ? idx_s[0] : 0;
        }
    }
    __syncthreads();   // idx_s ready for all waves

    // ---- phase 2: gather featT rows into LDS tile ----
    const int sm = tid >> 3;            // sample 0..31
    const int q8 = tid & 7;             // quarter-row 0..7
    const float4* base = featT4 + ((size_t)b * NPTS + idx_s[sm]) * 16;
    const float4 v0 = base[q8];
    const float4 v1 = base[8 + q8];

    const size_t cstride = (size_t)NQ * NS;
    const size_t out_q   = ((size_t)b * COUT * NQ + (size_t)p) * NS;

    // xyz channels (tid 0..31) overlap with the tile writes' latency
    float xv = 0.f, yv = 0.f, zv = 0.f;
    if (tid < NS) {
        const int j = idx_s[tid];
        xv = xb[j*3+0] - qx;
        yv = xb[j*3+1] - qy;
        zv = xb[j*3+2] - qz;
    }

    ((float4*)&tile[sm][q8 * 4])[0]      = v0;   // ds_write_b128
    ((float4*)&tile[sm][32 + q8 * 4])[0] = v1;

    if (tid < NS) {
        out[out_q + 0*cstride + tid] = xv;
        out[out_q + 1*cstride + tid] = yv;
        out[out_q + 2*cstride + tid] = zv;
    }
    __syncthreads();   // tile ready

    // stores: thread (s = tid&31, c8 = tid>>5) writes 8 channels
    const int s  = tid & 31;
    const int c8 = tid >> 5;
    float* ob = out + out_q + s + 3 * cstride;
    #pragma unroll
    for (int k = 0; k < 8; ++k) {
        const int c = c8 + k * 8;
        ob[(size_t)c * cstride] = tile[s][c];
    }
}

// ---------------- fallback: linear-scan kernel ----------------
__global__ __launch_bounds__(256) void qg_linear(
    const float* __restrict__ xyz, const float* __restrict__ new_xyz,
    const float* __restrict__ feat, float* __restrict__ out)
{
    const int wave = threadIdx.x >> 6;
    const int lane = threadIdx.x & 63;
    const int bp   = blockIdx.x * 4 + wave;
    const int b    = bp >> 12;
    const int p    = bp & (NQ - 1);
    __shared__ int idx_s[4][NS];
    const float qx = new_xyz[bp*3+0], qy = new_xyz[bp*3+1], qz = new_xyz[bp*3+2];
    const float* xb = xyz + (size_t)b * NPTS * 3;
    int cnt = 0;
    const unsigned long long below = (1ull << lane) - 1ull;
    for (int base = 0; base < NPTS; base += 64) {
        const int j = base + lane;
        const float dx = xb[j*3+0]-qx, dy = xb[j*3+1]-qy, dz = xb[j*3+2]-qz;
        const bool hit = dx*dx+dy*dy+dz*dz < R2;
        const unsigned long long m = __ballot(hit);
        if (hit) {
            const int slot = cnt + __popcll(m & below);
            if (slot < NS) idx_s[wave][slot] = j;
        }
        cnt += __popcll(m);
        if (cnt >= NS) break;
    }
    __builtin_amdgcn_wave_barrier();
    if (cnt < NS) {
        const int first = (cnt > 0) ? idx_s[wave][0] : 0;
        if (lane >= cnt && lane < NS) idx_s[wave][lane] = first;
    }
    __builtin_amdgcn_wave_barrier();
    const size_t cstride = (size_t)NQ * NS;
    const size_t out_q = ((size_t)b * COUT * NQ + (size_t)p) * NS;
    if (lane < NS) {
        const int j = idx_s[wave][lane];
        out[out_q + 0*cstride + lane] = xb[j*3+0] - qx;
        out[out_q + 1*cstride + lane] = xb[j*3+1] - qy;
        out[out_q + 2*cstride + lane] = xb[j*3+2] - qz;
    }
    const float* fb = feat + (size_t)b * CFEAT * NPTS;
    const int s = lane & 31, half = lane >> 5;
    const int j = idx_s[wave][s];
    #pragma unroll 8
    for (int c = half; c < CFEAT; c += 2)
        out[out_q + (size_t)(3 + c) * cstride + s] = fb[(size_t)c * NPTS + j];
}

extern "C" void kernel_launch(void* const* d_in, const int* in_sizes, int n_in,
                              void* d_out, int out_size, void* d_ws, size_t ws_size,
                              hipStream_t stream) {
    const float* xyz     = (const float*)d_in[0];  // (2,16384,3)
    const float* new_xyz = (const float*)d_in[1];  // (2,4096,3)
    const float* feat    = (const float*)d_in[2];  // (2,64,16384)
    float* out = (float*)d_out;                    // (2,67,4096,32)

    const size_t need_full = FEATT_BYTES + PXYZJ_BYTES + (size_t)GRID_INTS * sizeof(int);

    if (ws_size >= need_full) {
        float*  featT = (float*)d_ws;
        float4* pxyzj = (float4*)((char*)d_ws + FEATT_BYTES);
        int* gi = (int*)((char*)d_ws + FEATT_BYTES + PXYZJ_BYTES);
        int* cnt    = gi + OFF_CNT;
        int* fill   = gi + OFF_FILL;
        int* cstart = gi + OFF_CSTART;

        hipMemsetAsync(cnt, 0, 4 * NCELL * sizeof(int), stream);  // cnt + fill
        prep1_kernel<<<512 + (BATCH * NPTS) / 256, 256, 0, stream>>>(feat, featT, xyz, cnt);
        prep2_kernel<<<(BATCH * NPTS) / 256, 256, 0, stream>>>(xyz, cnt, fill, cstart, pxyzj);
        qg_fused<<<BATCH * NQ, 256, 0, stream>>>(
            xyz, new_xyz, cstart, pxyzj, (const float4*)featT, out);
    } else {
        qg_linear<<<(BATCH * NQ) / 4, 256, 0, stream>>>(xyz, new_xyz, feat, out);
    }
}

// Round 8
// 117.094 us; speedup vs baseline: 2.0216x; 1.0225x over previous
//
#include <hip/hip_runtime.h>
#include <hip/hip_bf16.h>
#include <climits>

#define BATCH   2
#define NPTS    16384   // N
#define NQ      4096    // P
#define CFEAT   64
#define NS      32      // nsample
#define R2      0.01f   // radius^2
#define COUT    (3 + CFEAT)   // 67
#define GDIM    10      // grid cells per axis (cell size = radius)
#define NCELL   (GDIM * GDIM * GDIM)
#define NWORDS  (NPTS / 32)   // 512 words per bitmask

// ---- ws layout (bytes) ----
// [0, 4MB)     : featT16 (B,N,C) bf16 (ushort)
// +512KB       : pxyzj   (B,N) float4 {x,y,z,bitcast(j)} cell-sorted
// then ints    : cnt[2*NCELL] | fill[2*NCELL] | cstart[2*(NCELL+1)]
#define FEATT_BYTES ((size_t)BATCH * NPTS * CFEAT * sizeof(unsigned short))
#define PXYZJ_BYTES ((size_t)BATCH * NPTS * sizeof(float4))
#define OFF_CNT    0
#define OFF_FILL   (2 * NCELL)
#define OFF_CSTART (4 * NCELL)
#define GRID_INTS  (4 * NCELL + 2 * (NCELL + 1))

__device__ __forceinline__ int cell_of(float x, float y, float z) {
    int cx = (int)(x * GDIM); cx = cx < 0 ? 0 : (cx > GDIM - 1 ? GDIM - 1 : cx);
    int cy = (int)(y * GDIM); cy = cy < 0 ? 0 : (cy > GDIM - 1 ? GDIM - 1 : cy);
    int cz = (int)(z * GDIM); cz = cz < 0 ? 0 : (cz > GDIM - 1 ? GDIM - 1 : cz);
    return (cz * GDIM + cy) * GDIM + cx;   // x fastest -> contiguous x-runs
}

__device__ __forceinline__ unsigned short f2bf(float f) {
    unsigned b = __float_as_uint(f);
    return (unsigned short)((b + 0x7FFFu + ((b >> 16) & 1u)) >> 16);   // RNE
}
__device__ __forceinline__ float bflo(unsigned u) { return __uint_as_float(u << 16); }
__device__ __forceinline__ float bfhi(unsigned u) { return __uint_as_float(u & 0xFFFF0000u); }

// ------- fused: transpose->bf16 (blocks 0..511) + count (blocks 512..639) ----
__global__ __launch_bounds__(256) void prep1_kernel(
    const float* __restrict__ feat, unsigned short* __restrict__ featT16,
    const float* __restrict__ xyz, int* __restrict__ cnt)
{
    __shared__ float tile[64][65];
    if (blockIdx.x < 512) {
        const int b    = blockIdx.x >> 8;
        const int n0   = (blockIdx.x & 255) * 64;
        const int lane = threadIdx.x & 63;
        const int grp  = threadIdx.x >> 6;           // 0..3
        const float* fb = feat + (size_t)b * CFEAT * NPTS;
        #pragma unroll
        for (int k = 0; k < 16; ++k) {
            const int c = grp * 16 + k;
            tile[c][lane] = fb[(size_t)c * NPTS + n0 + lane];
        }
        __syncthreads();
        // store bf16 (N,C): 2048 ushort2 per tile, 8 per thread
        unsigned short* db = featT16 + ((size_t)b * NPTS + n0) * CFEAT;
        #pragma unroll
        for (int k = 0; k < 8; ++k) {
            const int e   = threadIdx.x + 256 * k;
            const int row = e >> 5;           // 0..63 (point within tile)
            const int c2  = e & 31;           // channel pair
            ushort2 v;
            v.x = f2bf(tile[2 * c2][row]);
            v.y = f2bf(tile[2 * c2 + 1][row]);
            ((ushort2*)(db + (size_t)row * CFEAT))[c2] = v;
        }
    } else {
        const int g = (blockIdx.x - 512) * 256 + threadIdx.x;   // 0..B*N-1
        const int b = g >> 14;
        const int c = cell_of(xyz[g*3], xyz[g*3+1], xyz[g*3+2]);
        atomicAdd(&cnt[b * NCELL + c], 1);
    }
}

// ---------------- scan (redundant per block, in LDS) + scatter ----------------
__global__ __launch_bounds__(256) void prep2_kernel(
    const float* __restrict__ xyz, const int* __restrict__ cnt,
    int* __restrict__ fill, int* __restrict__ cstart,
    float4* __restrict__ pxyzj)
{
    __shared__ int scs[2 * NCELL];       // exclusive starts, both batches
    const int tid  = threadIdx.x;
    const int lane = tid & 63;

    if (tid < 128) {
        const int b = tid >> 6;
        int c16[16];
        int tot = 0;
        #pragma unroll
        for (int k = 0; k < 16; ++k) {
            const int i = lane * 16 + k;
            c16[k] = (i < NCELL) ? cnt[b * NCELL + i] : 0;
            tot += c16[k];
        }
        int ex = tot;
        #pragma unroll
        for (int off = 1; off < 64; off <<= 1) {
            const int u = __shfl_up(ex, off);
            if (lane >= off) ex += u;
        }
        ex -= tot;
        int run = ex;
        #pragma unroll
        for (int k = 0; k < 16; ++k) {
            const int i = lane * 16 + k;
            if (i < NCELL) scs[b * NCELL + i] = run;
            run += c16[k];
        }
    }
    __syncthreads();

    if (blockIdx.x == 0) {
        for (int i = tid; i < 2 * (NCELL + 1); i += 256) {
            const int b  = i / (NCELL + 1);
            const int ci = i - b * (NCELL + 1);
            cstart[i] = (ci == NCELL) ? NPTS : scs[b * NCELL + ci];
        }
    }

    const int g = blockIdx.x * 256 + tid;
    const int b = g >> 14;
    const int j = g & (NPTS - 1);
    const float x = xyz[g*3], y = xyz[g*3+1], z = xyz[g*3+2];
    const int c = cell_of(x, y, z);
    const int pos = atomicAdd(&fill[b * NCELL + c], 1);
    pxyzj[b * NPTS + scs[b * NCELL + c] + pos] =
        make_float4(x, y, z, __int_as_float(j));
}

// ---------------- fused main: one 256-thread block per query ----------------
__global__ __launch_bounds__(256) void qg_fused(
    const float* __restrict__ xyz,               // (B, N, 3)
    const float* __restrict__ new_xyz,           // (B, P, 3)
    const int* __restrict__ cstart,              // (B, NCELL+1)
    const float4* __restrict__ pxyzj,            // (B, N) sorted {x,y,z,j}
    const unsigned short* __restrict__ featT16,  // (B, N, C) bf16
    float* __restrict__ out)                     // (B, 67, P, S)
{
    const int q    = blockIdx.x;        // 0..B*P-1
    const int b    = q >> 12;
    const int p    = q & (NQ - 1);
    const int tid  = threadIdx.x;
    const int wave = tid >> 6;
    const int lane = tid & 63;

    __shared__ unsigned int hmask[NWORDS];   // 2KB block bitmask
    __shared__ int idx_s[NS];
    __shared__ float tile[NS][65];           // [sample][channel], +1 pad

    if (tid < 128) {
        uint4 z; z.x = 0; z.y = 0; z.z = 0; z.w = 0;
        ((uint4*)hmask)[tid] = z;
    }

    const float qx = new_xyz[q * 3 + 0];
    const float qy = new_xyz[q * 3 + 1];
    const float qz = new_xyz[q * 3 + 2];
    const float* xb = xyz + (size_t)b * NPTS * 3;
    const int* cs = cstart + b * (NCELL + 1);
    const float4* pb = pxyzj + (size_t)b * NPTS;

    int qcx = (int)(qx * GDIM); qcx = qcx < 0 ? 0 : (qcx > GDIM-1 ? GDIM-1 : qcx);
    int qcy = (int)(qy * GDIM); qcy = qcy < 0 ? 0 : (qcy > GDIM-1 ? GDIM-1 : qcy);
    int qcz = (int)(qz * GDIM); qcz = qcz < 0 ? 0 : (qcz > GDIM-1 ? GDIM-1 : qcz);
    const int x0 = qcx > 0 ? qcx - 1 : 0;
    const int x1 = qcx < GDIM-1 ? qcx + 1 : GDIM-1;
    const int y0 = qcy > 0 ? qcy - 1 : 0;
    const int y1 = qcy < GDIM-1 ? qcy + 1 : GDIM-1;
    const int z0 = qcz > 0 ? qcz - 1 : 0;
    const int z1 = qcz < GDIM-1 ? qcz + 1 : GDIM-1;
    const int ny  = y1 - y0 + 1;                 // 2 or 3
    const int nyz = ny * (z1 - z0 + 1);          // up to 9

    int sv = 0, ev = 0;
    if (lane < nyz) {
        const int gzi = (ny == 3) ? ((lane * 86) >> 8) : (lane >> 1);
        const int gyi = lane - gzi * ny;
        const int crow = ((z0 + gzi) * GDIM + (y0 + gyi)) * GDIM;
        sv = cs[crow + x0];
        ev = cs[crow + x1 + 1];
    }
    __syncthreads();   // bitmask zeroed

    for (int r = wave; r < nyz; r += 4) {
        const int s = __shfl(sv, r);
        const int e = __shfl(ev, r);
        for (int pos = s; pos < e; pos += 64) {
            const int i = pos + lane;
            const bool inr = i < e;
            const float4 pt = pb[inr ? i : 0];   // coalesced dwordx4
            const float dx = pt.x - qx;
            const float dy = pt.y - qy;
            const float dz = pt.z - qz;
            if (inr && (dx*dx + dy*dy + dz*dz < R2)) {
                const int j = __float_as_int(pt.w);
                atomicOr(&hmask[j >> 5], 1u << (j & 31));
            }
        }
    }
    __syncthreads();   // all hits in bitmask

    // ---- extraction: ALL waves redundantly (identical values; benign race) --
    {
        unsigned int w[8];
        const uint4 a = ((const uint4*)hmask)[lane * 2];
        const uint4 c = ((const uint4*)hmask)[lane * 2 + 1];
        w[0] = a.x; w[1] = a.y; w[2] = a.z; w[3] = a.w;
        w[4] = c.x; w[5] = c.y; w[6] = c.z; w[7] = c.w;

        int cnt8 = 0;
        #pragma unroll
        for (int k = 0; k < 8; ++k) cnt8 += __popc(w[k]);

        int pfx = cnt8;
        #pragma unroll
        for (int off = 1; off < 64; off <<= 1) {
            const int u = __shfl_up(pfx, off);
            if (lane >= off) pfx += u;
        }
        const int K = __shfl(pfx, 63);
        pfx -= cnt8;

        if (pfx < NS && cnt8 > 0) {
            int r = pfx;
            #pragma unroll
            for (int k = 0; k < 8; ++k) {
                unsigned int m = w[k];
                while (m && r < NS) {
                    const int bit = __builtin_ctz(m);
                    idx_s[r] = lane * 256 + k * 32 + bit;
                    m &= m - 1;
                    ++r;
                }
            }
        }
        __builtin_amdgcn_wave_barrier();
        if (lane < NS && lane >= K) {
            idx_s[lane] = (K > 0) ? idx_s[0] : 0;
        }
        __builtin_amdgcn_wave_barrier();
        // each wave wrote the full idx_s itself -> no __syncthreads needed
    }

    // ---- phase 2: gather bf16 featT rows into fp32 LDS tile ----
    const int sm = tid >> 3;            // sample 0..31
    const int q8 = tid & 7;             // eighth-row 0..7 (8 channels each)
    const unsigned short* base16 = featT16 + ((size_t)b * NPTS + idx_s[sm]) * CFEAT;
    const uint4 v = ((const uint4*)base16)[q8];

    const size_t cstride = (size_t)NQ * NS;
    const size_t out_q   = ((size_t)b * COUT * NQ + (size_t)p) * NS;

    // xyz channels (tid 0..31), overlapping the gather loads' latency
    float xv = 0.f, yv = 0.f, zv = 0.f;
    if (tid < NS) {
        const int j = idx_s[tid];
        xv = xb[j*3+0] - qx;
        yv = xb[j*3+1] - qy;
        zv = xb[j*3+2] - qz;
    }

    float4 lo, hi;
    lo.x = bflo(v.x); lo.y = bfhi(v.x); lo.z = bflo(v.y); lo.w = bfhi(v.y);
    hi.x = bflo(v.z); hi.y = bfhi(v.z); hi.z = bflo(v.w); hi.w = bfhi(v.w);
    ((float4*)&tile[sm][q8 * 8])[0]     = lo;   // ds_write_b128
    ((float4*)&tile[sm][q8 * 8 + 4])[0] = hi;

    if (tid < NS) {
        out[out_q + 0*cstride + tid] = xv;
        out[out_q + 1*cstride + tid] = yv;
        out[out_q + 2*cstride + tid] = zv;
    }
    __syncthreads();   // tile ready

    // stores: thread (s = tid&31, c8 = tid>>5) writes 8 channels
    const int s  = tid & 31;
    const int c8 = tid >> 5;
    float* ob = out + out_q + s + 3 * cstride;
    #pragma unroll
    for (int k = 0; k < 8; ++k) {
        const int c = c8 + k * 8;
        ob[(size_t)c * cstride] = tile[s][c];
    }
}

// ---------------- fallback: linear-scan kernel (fp32 exact) ----------------
__global__ __launch_bounds__(256) void qg_linear(
    const float* __restrict__ xyz, const float* __restrict__ new_xyz,
    const float* __restrict__ feat, float* __restrict__ out)
{
    const int wave = threadIdx.x >> 6;
    const int lane = threadIdx.x & 63;
    const int bp   = blockIdx.x * 4 + wave;
    const int b    = bp >> 12;
    const int p    = bp & (NQ - 1);
    __shared__ int idx_s[4][NS];
    const float qx = new_xyz[bp*3+0], qy = new_xyz[bp*3+1], qz = new_xyz[bp*3+2];
    const float* xb = xyz + (size_t)b * NPTS * 3;
    int cnt = 0;
    const unsigned long long below = (1ull << lane) - 1ull;
    for (int base = 0; base < NPTS; base += 64) {
        const int j = base + lane;
        const float dx = xb[j*3+0]-qx, dy = xb[j*3+1]-qy, dz = xb[j*3+2]-qz;
        const bool hit = dx*dx+dy*dy+dz*dz < R2;
        const unsigned long long m = __ballot(hit);
        if (hit) {
            const int slot = cnt + __popcll(m & below);
            if (slot < NS) idx_s[wave][slot] = j;
        }
        cnt += __popcll(m);
        if (cnt >= NS) break;
    }
    __builtin_amdgcn_wave_barrier();
    if (cnt < NS) {
        const int first = (cnt > 0) ? idx_s[wave][0] : 0;
        if (lane >= cnt && lane < NS) idx_s[wave][lane] = first;
    }
    __builtin_amdgcn_wave_barrier();
    const size_t cstride = (size_t)NQ * NS;
    const size_t out_q = ((size_t)b * COUT * NQ + (size_t)p) * NS;
    if (lane < NS) {
        const int j = idx_s[wave][lane];
        out[out_q + 0*cstride + lane] = xb[j*3+0] - qx;
        out[out_q + 1*cstride + lane] = xb[j*3+1] - qy;
        out[out_q + 2*cstride + lane] = xb[j*3+2] - qz;
    }
    const float* fb = feat + (size_t)b * CFEAT * NPTS;
    const int s = lane & 31, half = lane >> 5;
    const int j = idx_s[wave][s];
    #pragma unroll 8
    for (int c = half; c < CFEAT; c += 2)
        out[out_q + (size_t)(3 + c) * cstride + s] = fb[(size_t)c * NPTS + j];
}

extern "C" void kernel_launch(void* const* d_in, const int* in_sizes, int n_in,
                              void* d_out, int out_size, void* d_ws, size_t ws_size,
                              hipStream_t stream) {
    const float* xyz     = (const float*)d_in[0];  // (2,16384,3)
    const float* new_xyz = (const float*)d_in[1];  // (2,4096,3)
    const float* feat    = (const float*)d_in[2];  // (2,64,16384)
    float* out = (float*)d_out;                    // (2,67,4096,32)

    const size_t need_full = FEATT_BYTES + PXYZJ_BYTES + (size_t)GRID_INTS * sizeof(int);

    if (ws_size >= need_full) {
        unsigned short* featT16 = (unsigned short*)d_ws;
        float4* pxyzj = (float4*)((char*)d_ws + FEATT_BYTES);
        int* gi = (int*)((char*)d_ws + FEATT_BYTES + PXYZJ_BYTES);
        int* cnt    = gi + OFF_CNT;
        int* fill   = gi + OFF_FILL;
        int* cstart = gi + OFF_CSTART;

        hipMemsetAsync(cnt, 0, 4 * NCELL * sizeof(int), stream);  // cnt + fill
        prep1_kernel<<<512 + (BATCH * NPTS) / 256, 256, 0, stream>>>(feat, featT16, xyz, cnt);
        prep2_kernel<<<(BATCH * NPTS) / 256, 256, 0, stream>>>(xyz, cnt, fill, cstart, pxyzj);
        qg_fused<<<BATCH * NQ, 256, 0, stream>>>(
            xyz, new_xyz, cstart, pxyzj, featT16, out);
    } else {
        qg_linear<<<(BATCH * NQ) / 4, 256, 0, stream>>>(xyz, new_xyz, feat, out);
    }
}

// Round 9
// 114.113 us; speedup vs baseline: 2.0744x; 1.0261x over previous
//
#include <hip/hip_runtime.h>
#include <hip/hip_bf16.h>
#include <climits>

#define BATCH   2
#define NPTS    16384   // N
#define NQ      4096    // P
#define CFEAT   64
#define NS      32      // nsample
#define R2      0.01f   // radius^2
#define COUT    (3 + CFEAT)   // 67
#define GDIM    10      // grid cells per axis (cell size = radius)
#define NCELL   (GDIM * GDIM * GDIM)
#define NWORDS  (NPTS / 32)   // 512 words per bitmask

// ---- ws layout (bytes) ----
// [0, 4MB)     : featT16 (B,N,C) bf16 (ushort)
// +512KB       : pxyzj   (B,N) float4 {x,y,z,bitcast(j)} cell-sorted
// then ints    : cnt[2*NCELL] | fill[2*NCELL] | cstart[2*(NCELL+1)]
#define FEATT_BYTES ((size_t)BATCH * NPTS * CFEAT * sizeof(unsigned short))
#define PXYZJ_BYTES ((size_t)BATCH * NPTS * sizeof(float4))
#define OFF_CNT    0
#define OFF_FILL   (2 * NCELL)
#define OFF_CSTART (4 * NCELL)
#define GRID_INTS  (4 * NCELL + 2 * (NCELL + 1))

__device__ __forceinline__ int cell_of(float x, float y, float z) {
    int cx = (int)(x * GDIM); cx = cx < 0 ? 0 : (cx > GDIM - 1 ? GDIM - 1 : cx);
    int cy = (int)(y * GDIM); cy = cy < 0 ? 0 : (cy > GDIM - 1 ? GDIM - 1 : cy);
    int cz = (int)(z * GDIM); cz = cz < 0 ? 0 : (cz > GDIM - 1 ? GDIM - 1 : cz);
    return (cz * GDIM + cy) * GDIM + cx;   // x fastest -> contiguous x-runs
}

__device__ __forceinline__ unsigned short f2bf(float f) {
    unsigned b = __float_as_uint(f);
    return (unsigned short)((b + 0x7FFFu + ((b >> 16) & 1u)) >> 16);   // RNE
}
__device__ __forceinline__ float bflo(unsigned u) { return __uint_as_float(u << 16); }
__device__ __forceinline__ float bfhi(unsigned u) { return __uint_as_float(u & 0xFFFF0000u); }

// ------- fused: transpose->bf16 (blocks 0..511) + count (blocks 512..639) ----
__global__ __launch_bounds__(256) void prep1_kernel(
    const float* __restrict__ feat, unsigned short* __restrict__ featT16,
    const float* __restrict__ xyz, int* __restrict__ cnt)
{
    __shared__ float tile[64][65];
    if (blockIdx.x < 512) {
        const int b    = blockIdx.x >> 8;
        const int n0   = (blockIdx.x & 255) * 64;
        const int lane = threadIdx.x & 63;
        const int grp  = threadIdx.x >> 6;           // 0..3
        const float* fb = feat + (size_t)b * CFEAT * NPTS;
        #pragma unroll
        for (int k = 0; k < 16; ++k) {
            const int c = grp * 16 + k;
            tile[c][lane] = fb[(size_t)c * NPTS + n0 + lane];
        }
        __syncthreads();
        unsigned short* db = featT16 + ((size_t)b * NPTS + n0) * CFEAT;
        #pragma unroll
        for (int k = 0; k < 8; ++k) {
            const int e   = threadIdx.x + 256 * k;
            const int row = e >> 5;           // 0..63 (point within tile)
            const int c2  = e & 31;           // channel pair
            ushort2 v;
            v.x = f2bf(tile[2 * c2][row]);
            v.y = f2bf(tile[2 * c2 + 1][row]);
            ((ushort2*)(db + (size_t)row * CFEAT))[c2] = v;
        }
    } else {
        const int g = (blockIdx.x - 512) * 256 + threadIdx.x;   // 0..B*N-1
        const int b = g >> 14;
        const int c = cell_of(xyz[g*3], xyz[g*3+1], xyz[g*3+2]);
        atomicAdd(&cnt[b * NCELL + c], 1);
    }
}

// ---------------- scan (redundant per block, in LDS) + scatter ----------------
__global__ __launch_bounds__(256) void prep2_kernel(
    const float* __restrict__ xyz, const int* __restrict__ cnt,
    int* __restrict__ fill, int* __restrict__ cstart,
    float4* __restrict__ pxyzj)
{
    __shared__ int scs[2 * NCELL];       // exclusive starts, both batches
    const int tid  = threadIdx.x;
    const int lane = tid & 63;

    if (tid < 128) {
        const int b = tid >> 6;
        int c16[16];
        int tot = 0;
        #pragma unroll
        for (int k = 0; k < 16; ++k) {
            const int i = lane * 16 + k;
            c16[k] = (i < NCELL) ? cnt[b * NCELL + i] : 0;
            tot += c16[k];
        }
        int ex = tot;
        #pragma unroll
        for (int off = 1; off < 64; off <<= 1) {
            const int u = __shfl_up(ex, off);
            if (lane >= off) ex += u;
        }
        ex -= tot;
        int run = ex;
        #pragma unroll
        for (int k = 0; k < 16; ++k) {
            const int i = lane * 16 + k;
            if (i < NCELL) scs[b * NCELL + i] = run;
            run += c16[k];
        }
    }
    __syncthreads();

    if (blockIdx.x == 0) {
        for (int i = tid; i < 2 * (NCELL + 1); i += 256) {
            const int b  = i / (NCELL + 1);
            const int ci = i - b * (NCELL + 1);
            cstart[i] = (ci == NCELL) ? NPTS : scs[b * NCELL + ci];
        }
    }

    const int g = blockIdx.x * 256 + tid;
    const int b = g >> 14;
    const int j = g & (NPTS - 1);
    const float x = xyz[g*3], y = xyz[g*3+1], z = xyz[g*3+2];
    const int c = cell_of(x, y, z);
    const int pos = atomicAdd(&fill[b * NCELL + c], 1);
    pxyzj[b * NPTS + scs[b * NCELL + c] + pos] =
        make_float4(x, y, z, __int_as_float(j));
}

// ---------------- fused main: one 128-thread block (2 waves) per query -------
// LDS: hmask (2KB) unioned with tile (8.3KB) -> 8.45KB/block, 16 blocks/CU.
__global__ __launch_bounds__(128) void qg_fused(
    const float* __restrict__ xyz,               // (B, N, 3)
    const float* __restrict__ new_xyz,           // (B, P, 3)
    const int* __restrict__ cstart,              // (B, NCELL+1)
    const float4* __restrict__ pxyzj,            // (B, N) sorted {x,y,z,j}
    const unsigned short* __restrict__ featT16,  // (B, N, C) bf16
    float* __restrict__ out)                     // (B, 67, P, S)
{
    const int q    = blockIdx.x;        // 0..B*P-1
    const int b    = q >> 12;
    const int p    = q & (NQ - 1);
    const int tid  = threadIdx.x;       // 0..127
    const int wave = tid >> 6;          // 0 or 1
    const int lane = tid & 63;

    __shared__ __align__(16) unsigned char smem[NS * 65 * sizeof(float)]; // 8320B
    unsigned int* hmask = (unsigned int*)smem;          // phase 1: 512 words
    float (*tile)[65]   = (float(*)[65])smem;           // phase 2: 32 x 65
    __shared__ int idx_s[NS];

    // zero bitmask: 128 threads x 1 uint4 = 2KB
    {
        uint4 z; z.x = 0; z.y = 0; z.z = 0; z.w = 0;
        ((uint4*)hmask)[tid] = z;
    }

    const float qx = new_xyz[q * 3 + 0];
    const float qy = new_xyz[q * 3 + 1];
    const float qz = new_xyz[q * 3 + 2];
    const float* xb = xyz + (size_t)b * NPTS * 3;
    const int* cs = cstart + b * (NCELL + 1);
    const float4* pb = pxyzj + (size_t)b * NPTS;

    int qcx = (int)(qx * GDIM); qcx = qcx < 0 ? 0 : (qcx > GDIM-1 ? GDIM-1 : qcx);
    int qcy = (int)(qy * GDIM); qcy = qcy < 0 ? 0 : (qcy > GDIM-1 ? GDIM-1 : qcy);
    int qcz = (int)(qz * GDIM); qcz = qcz < 0 ? 0 : (qcz > GDIM-1 ? GDIM-1 : qcz);
    const int x0 = qcx > 0 ? qcx - 1 : 0;
    const int x1 = qcx < GDIM-1 ? qcx + 1 : GDIM-1;
    const int y0 = qcy > 0 ? qcy - 1 : 0;
    const int y1 = qcy < GDIM-1 ? qcy + 1 : GDIM-1;
    const int z0 = qcz > 0 ? qcz - 1 : 0;
    const int z1 = qcz < GDIM-1 ? qcz + 1 : GDIM-1;
    const int ny  = y1 - y0 + 1;                 // 2 or 3
    const int nyz = ny * (z1 - z0 + 1);          // up to 9

    int sv = 0, ev = 0;
    if (lane < nyz) {
        const int gzi = (ny == 3) ? ((lane * 86) >> 8) : (lane >> 1);
        const int gyi = lane - gzi * ny;
        const int crow = ((z0 + gzi) * GDIM + (y0 + gyi)) * GDIM;
        sv = cs[crow + x0];
        ev = cs[crow + x1 + 1];
    }
    __syncthreads();   // bitmask zeroed

    for (int r = wave; r < nyz; r += 2) {
        const int s = __shfl(sv, r);
        const int e = __shfl(ev, r);
        for (int pos = s; pos < e; pos += 64) {
            const int i = pos + lane;
            const bool inr = i < e;
            const float4 pt = pb[inr ? i : 0];   // coalesced dwordx4
            const float dx = pt.x - qx;
            const float dy = pt.y - qy;
            const float dz = pt.z - qz;
            if (inr && (dx*dx + dy*dy + dz*dz < R2)) {
                const int j = __float_as_int(pt.w);
                atomicOr(&hmask[j >> 5], 1u << (j & 31));
            }
        }
    }
    __syncthreads();   // all hits in bitmask

    // ---- extraction: both waves redundantly (identical values) ----
    {
        unsigned int w[8];
        const uint4 a = ((const uint4*)hmask)[lane * 2];
        const uint4 c = ((const uint4*)hmask)[lane * 2 + 1];
        w[0] = a.x; w[1] = a.y; w[2] = a.z; w[3] = a.w;
        w[4] = c.x; w[5] = c.y; w[6] = c.z; w[7] = c.w;

        int cnt8 = 0;
        #pragma unroll
        for (int k = 0; k < 8; ++k) cnt8 += __popc(w[k]);

        int pfx = cnt8;
        #pragma unroll
        for (int off = 1; off < 64; off <<= 1) {
            const int u = __shfl_up(pfx, off);
            if (lane >= off) pfx += u;
        }
        const int K = __shfl(pfx, 63);
        pfx -= cnt8;

        if (pfx < NS && cnt8 > 0) {
            int r = pfx;
            #pragma unroll
            for (int k = 0; k < 8; ++k) {
                unsigned int m = w[k];
                while (m && r < NS) {
                    const int bit = __builtin_ctz(m);
                    idx_s[r] = lane * 256 + k * 32 + bit;
                    m &= m - 1;
                    ++r;
                }
            }
        }
        __builtin_amdgcn_wave_barrier();
        if (lane < NS && lane >= K) {
            idx_s[lane] = (K > 0) ? idx_s[0] : 0;
        }
        __builtin_amdgcn_wave_barrier();
    }

    // ---- phase 2: issue gather loads BEFORE the union sync ----
    const int sm = tid >> 2;            // sample 0..31
    const int q4 = tid & 3;             // quarter-row 0..3 (16 channels each)
    const unsigned short* base16 = featT16 + ((size_t)b * NPTS + idx_s[sm]) * CFEAT;
    const uint4 va = ((const uint4*)base16)[q4 * 2];
    const uint4 vb = ((const uint4*)base16)[q4 * 2 + 1];

    const size_t cstride = (size_t)NQ * NS;
    const size_t out_q   = ((size_t)b * COUT * NQ + (size_t)p) * NS;

    float xv = 0.f, yv = 0.f, zv = 0.f;
    if (tid < NS) {
        const int j = idx_s[tid];
        xv = xb[j*3+0] - qx;
        yv = xb[j*3+1] - qy;
        zv = xb[j*3+2] - qz;
    }
    __syncthreads();   // union boundary: hmask reads done -> tile writable

    float4 f0, f1, f2, f3;
    f0.x = bflo(va.x); f0.y = bfhi(va.x); f0.z = bflo(va.y); f0.w = bfhi(va.y);
    f1.x = bflo(va.z); f1.y = bfhi(va.z); f1.z = bflo(va.w); f1.w = bfhi(va.w);
    f2.x = bflo(vb.x); f2.y = bfhi(vb.x); f2.z = bflo(vb.y); f2.w = bfhi(vb.y);
    f3.x = bflo(vb.z); f3.y = bfhi(vb.z); f3.z = bflo(vb.w); f3.w = bfhi(vb.w);
    ((float4*)&tile[sm][q4 * 16])[0]      = f0;
    ((float4*)&tile[sm][q4 * 16 + 4])[0]  = f1;
    ((float4*)&tile[sm][q4 * 16 + 8])[0]  = f2;
    ((float4*)&tile[sm][q4 * 16 + 12])[0] = f3;

    if (tid < NS) {
        out[out_q + 0*cstride + tid] = xv;
        out[out_q + 1*cstride + tid] = yv;
        out[out_q + 2*cstride + tid] = zv;
    }
    __syncthreads();   // tile ready

    // stores: thread (s = tid&31, c4 = tid>>5) writes 16 channels
    const int s  = tid & 31;
    const int c4 = tid >> 5;            // 0..3
    float* ob = out + out_q + s + 3 * cstride;
    #pragma unroll
    for (int k = 0; k < 16; ++k) {
        const int c = c4 + k * 4;
        ob[(size_t)c * cstride] = tile[s][c];
    }
}

// ---------------- fallback: linear-scan kernel (fp32 exact) ----------------
__global__ __launch_bounds__(256) void qg_linear(
    const float* __restrict__ xyz, const float* __restrict__ new_xyz,
    const float* __restrict__ feat, float* __restrict__ out)
{
    const int wave = threadIdx.x >> 6;
    const int lane = threadIdx.x & 63;
    const int bp   = blockIdx.x * 4 + wave;
    const int b    = bp >> 12;
    const int p    = bp & (NQ - 1);
    __shared__ int idx_s[4][NS];
    const float qx = new_xyz[bp*3+0], qy = new_xyz[bp*3+1], qz = new_xyz[bp*3+2];
    const float* xb = xyz + (size_t)b * NPTS * 3;
    int cnt = 0;
    const unsigned long long below = (1ull << lane) - 1ull;
    for (int base = 0; base < NPTS; base += 64) {
        const int j = base + lane;
        const float dx = xb[j*3+0]-qx, dy = xb[j*3+1]-qy, dz = xb[j*3+2]-qz;
        const bool hit = dx*dx+dy*dy+dz*dz < R2;
        const unsigned long long m = __ballot(hit);
        if (hit) {
            const int slot = cnt + __popcll(m & below);
            if (slot < NS) idx_s[wave][slot] = j;
        }
        cnt += __popcll(m);
        if (cnt >= NS) break;
    }
    __builtin_amdgcn_wave_barrier();
    if (cnt < NS) {
        const int first = (cnt > 0) ? idx_s[wave][0] : 0;
        if (lane >= cnt && lane < NS) idx_s[wave][lane] = first;
    }
    __builtin_amdgcn_wave_barrier();
    const size_t cstride = (size_t)NQ * NS;
    const size_t out_q = ((size_t)b * COUT * NQ + (size_t)p) * NS;
    if (lane < NS) {
        const int j = idx_s[wave][lane];
        out[out_q + 0*cstride + lane] = xb[j*3+0] - qx;
        out[out_q + 1*cstride + lane] = xb[j*3+1] - qy;
        out[out_q + 2*cstride + lane] = xb[j*3+2] - qz;
    }
    const float* fb = feat + (size_t)b * CFEAT * NPTS;
    const int s = lane & 31, half = lane >> 5;
    const int j = idx_s[wave][s];
    #pragma unroll 8
    for (int c = half; c < CFEAT; c += 2)
        out[out_q + (size_t)(3 + c) * cstride + s] = fb[(size_t)c * NPTS + j];
}

extern "C" void kernel_launch(void* const* d_in, const int* in_sizes, int n_in,
                              void* d_out, int out_size, void* d_ws, size_t ws_size,
                              hipStream_t stream) {
    const float* xyz     = (const float*)d_in[0];  // (2,16384,3)
    const float* new_xyz = (const float*)d_in[1];  // (2,4096,3)
    const float* feat    = (const float*)d_in[2];  // (2,64,16384)
    float* out = (float*)d_out;                    // (2,67,4096,32)

    const size_t need_full = FEATT_BYTES + PXYZJ_BYTES + (size_t)GRID_INTS * sizeof(int);

    if (ws_size >= need_full) {
        unsigned short* featT16 = (unsigned short*)d_ws;
        float4* pxyzj = (float4*)((char*)d_ws + FEATT_BYTES);
        int* gi = (int*)((char*)d_ws + FEATT_BYTES + PXYZJ_BYTES);
        int* cnt    = gi + OFF_CNT;
        int* fill   = gi + OFF_FILL;
        int* cstart = gi + OFF_CSTART;

        hipMemsetAsync(cnt, 0, 4 * NCELL * sizeof(int), stream);  // cnt + fill
        prep1_kernel<<<512 + (BATCH * NPTS) / 256, 256, 0, stream>>>(feat, featT16, xyz, cnt);
        prep2_kernel<<<(BATCH * NPTS) / 256, 256, 0, stream>>>(xyz, cnt, fill, cstart, pxyzj);
        qg_fused<<<BATCH * NQ, 128, 0, stream>>>(
            xyz, new_xyz, cstart, pxyzj, featT16, out);
    } else {
        qg_linear<<<(BATCH * NQ) / 4, 256, 0, stream>>>(xyz, new_xyz, feat, out);
    }
}